// Round 7
// baseline (1134.596 us; speedup 1.0000x reference)
//
#include <hip/hip_runtime.h>
#include <hip/hip_bf16.h>
#include <math.h>

#define EMB 64
#define CAPB 3584      // per-bucket slot capacity (mean 3125, sigma ~56 -> 8.2 sigma)
#define CHUNK 4096     // edges per bin_edges block

// ---------------- bucket-sort CSR build ----------------
// Buckets: BU=512 (user), BI=256 (item); RPB = ceil(n/B) rows per bucket (196).
// Record: int2( col | (inrow<<17), f32val )  [col<2^17, inrow<256]

__global__ void init_cursors(int* gcurU, int* gcurI, int BU, int BI) {
    int i = blockIdx.x * blockDim.x + threadIdx.x;
    if (i < BU) gcurU[i * 16] = i * CAPB;
    else if (i < BU + BI) gcurI[(i - BU) * 16] = (i - BU) * CAPB;
}

__global__ __launch_bounds__(256) void bin_edges(
    const int* __restrict__ rows, const int* __restrict__ cols,
    const float* __restrict__ vals, int nE, int B, int RPB,
    int* gcur, int2* __restrict__ binned) {
    __shared__ int cnt[512];
    __shared__ int lbase[512];
    int t = threadIdx.x;
    for (int i = t; i < B; i += 256) cnt[i] = 0;
    __syncthreads();
    int c0 = blockIdx.x * CHUNK;
    int bs[16];
#pragma unroll
    for (int j = 0; j < 16; ++j) {
        int idx = c0 + t + j * 256;
        int bsv = -1;
        if (idx < nE) {
            int row = rows[idx];
            int b = row / RPB;
            int slot = atomicAdd(&cnt[b], 1);
            bsv = (b << 16) | slot;
        }
        bs[j] = bsv;
    }
    __syncthreads();
    for (int i = t; i < B; i += 256) {
        int c = cnt[i];
        lbase[i] = c ? atomicAdd(&gcur[i * 16], c) : 0;
    }
    __syncthreads();
#pragma unroll
    for (int j = 0; j < 16; ++j) {
        int idx = c0 + t + j * 256;
        if (idx >= nE) continue;
        int bsv = bs[j];
        int b = bsv >> 16, slot = bsv & 0xFFFF;
        int row = rows[idx];          // L1/L2-hot re-read
        int col = cols[idx];
        float v = vals[idx];
        int inrow = row - b * RPB;
        int pos = lbase[b] + slot;
        if (pos < (b + 1) * CAPB)
            binned[pos] = make_int2(col | (inrow << 17), __float_as_int(v));
    }
}

// inclusive scan across a 1024-thread block; wsum is 16-int shared
__device__ __forceinline__ int block_scan_1024(int v, int* wsum) {
    int tid = threadIdx.x, lane = tid & 63, wid = tid >> 6;
    int s = v;
#pragma unroll
    for (int d = 1; d < 64; d <<= 1) {
        int t = __shfl_up(s, d);
        if (lane >= d) s += t;
    }
    if (lane == 63) wsum[wid] = s;
    __syncthreads();
    if (tid < 16) {
        int ws = wsum[tid];
#pragma unroll
        for (int d = 1; d < 16; d <<= 1) {
            int t = __shfl_up(ws, d);
            if (tid >= d) ws += t;
        }
        wsum[tid] = ws;
    }
    __syncthreads();
    int wpref = (wid > 0) ? wsum[wid - 1] : 0;
    return wpref + s;
}

// block 0: user buckets, block 1: item buckets. cntb[b], ebase[b] (exclusive)
__global__ void scan_buckets(const int* __restrict__ gcurU, int BU, int* cntbU, int* ebaseU,
                             const int* __restrict__ gcurI, int BI, int* cntbI, int* ebaseI) {
    __shared__ int wsum[16];
    const int* gcur; int B; int* cntb; int* ebase;
    if (blockIdx.x == 0) { gcur = gcurU; B = BU; cntb = cntbU; ebase = ebaseU; }
    else { gcur = gcurI; B = BI; cntb = cntbI; ebase = ebaseI; }
    int t = threadIdx.x;
    int v = 0;
    if (t < B) {
        v = gcur[t * 16] - t * CAPB;
        if (v < 0) v = 0;
        if (v > CAPB) v = CAPB;
    }
    int incl = block_scan_1024(v, wsum);
    if (t < B) { cntb[t] = v; ebase[t] = incl - v; }
}

// one workgroup per bucket: stage records in LDS, count rows, scan, emit CSR
__global__ __launch_bounds__(256) void finalize_csr(
    const int2* __restrict__ binned, const int* __restrict__ cntb,
    const int* __restrict__ ebase, int RPB, int n,
    int2* __restrict__ ccv, int* __restrict__ off) {
    __shared__ int2 rec[CAPB];
    __shared__ int cnt_r[256];
    __shared__ int excl[257];
    __shared__ int curs[256];
    int b = blockIdx.x;
    int t = threadIdx.x;
    int r0 = b * RPB;
    int nrows = n - r0; if (nrows > RPB) nrows = RPB;
    if (nrows <= 0) return;
    int cnt = cntb[b];
    int eb  = ebase[b];
    const int2* src = binned + (size_t)b * CAPB;
    cnt_r[t] = 0;
    __syncthreads();
    for (int p = t; p < cnt; p += 256) {
        int2 r = src[p];
        rec[p] = r;
        atomicAdd(&cnt_r[(r.x >> 17) & 0xFF], 1);
    }
    __syncthreads();
    // exclusive scan of 256 counters: wave 0, 4 segments of 64 with carry
    if (t < 64) {
        int carry = 0;
#pragma unroll
        for (int seg = 0; seg < 4; ++seg) {
            int i = seg * 64 + t;
            int v = cnt_r[i];
            int s = v;
#pragma unroll
            for (int d = 1; d < 64; d <<= 1) {
                int u2 = __shfl_up(s, d);
                if (t >= d) s += u2;
            }
            excl[i] = carry + s - v;
            carry += __shfl(s, 63);
        }
        if (t == 0) excl[256] = carry;
    }
    __syncthreads();
    curs[t] = excl[t];
    if (t < nrows) off[r0 + t] = eb + excl[t];
    if (t == 0 && r0 + nrows == n) off[n] = eb + cnt;
    __syncthreads();
    for (int p = t; p < cnt; p += 256) {
        int2 r = rec[p];
        int inrow = (r.x >> 17) & 0xFF;
        int slot = atomicAdd(&curs[inrow], 1);
        ccv[eb + slot] = make_int2(r.x & 0x1FFFF, r.y);
    }
}

// ---------------- f32 -> bf16 cast (RNE), vectorized ----------------

__device__ __forceinline__ ushort bf16_rne(float f) {
    uint u = __float_as_uint(f);
    return (ushort)((u + 0x7fffu + ((u >> 16) & 1u)) >> 16);
}

__global__ void cast_bf16(const float4* __restrict__ au, ushort* __restrict__ ou, long n4u,
                          const float4* __restrict__ ai, ushort* __restrict__ oi, long n4i) {
    long i = (long)blockIdx.x * blockDim.x + threadIdx.x;
    long tot = n4u + n4i;
    if (i >= tot) return;
    const float4* a; ushort* o; long j;
    if (i < n4u) { a = au; o = ou; j = i; }
    else { a = ai; o = oi; j = i - n4u; }
    float4 v = a[j];
    ushort4 r;
    r.x = bf16_rne(v.x); r.y = bf16_rne(v.y); r.z = bf16_rne(v.z); r.w = bf16_rne(v.w);
    *(ushort4*)(o + j * 4) = r;
}

// ---------------- fused SPMM + dense(x@W^T+b) + leaky_relu + L2 norm ----------------
// Wave split into 4 groups of 16 lanes; each group gathers ONE edge's 64-feature bf16
// row as uint2 (8B/lane) -> one VMEM instruction moves 4 edges (512B).
// lane = q + 16*g: q = feature quad, g = edge group.
// W held per-wave as 32 bf16x2-packed VGPRs (not 64 f32 -> frees regs for occupancy).
// x and y MUST be distinct buffers (gather reads random rows).

__global__ __launch_bounds__(256, 6) void spmm_dense_norm(
    const int* __restrict__ uoff, const int2* __restrict__ ccvU,
    const ushort* __restrict__ xu, const float* __restrict__ Wu, const float* __restrict__ bu,
    float* __restrict__ yfu, ushort* __restrict__ ybu, int nu, int gbu,
    const int* __restrict__ ioff, const int2* __restrict__ ccvI,
    const ushort* __restrict__ xi, const float* __restrict__ Wi, const float* __restrict__ bi,
    float* __restrict__ yfi, ushort* __restrict__ ybi, int ni) {
    int lane = threadIdx.x & 63, wid = threadIdx.x >> 6;
    int q = lane & 15, g = lane >> 4;
    const int* off; const int2* ccv; const ushort* x; const float* W; const float* bv;
    float* yf; ushort* yb; int n; int b; int nblocks;
    if ((int)blockIdx.x < gbu) {
        off = uoff; ccv = ccvU; x = xu; W = Wu; bv = bu; yf = yfu; yb = ybu; n = nu;
        b = blockIdx.x; nblocks = gbu;
    } else {
        off = ioff; ccv = ccvI; x = xi; W = Wi; bv = bi; yf = yfi; yb = ybi; n = ni;
        b = blockIdx.x - gbu; nblocks = gridDim.x - gbu;
    }
    const uint2* xv2 = (const uint2*)x;
    // pack W[lane][2m], W[lane][2m+1] as bf16 pair in one uint
    uint wpk[EMB / 2];
#pragma unroll
    for (int m = 0; m < EMB / 2; ++m) {
        float w0 = W[lane * EMB + 2 * m];
        float w1 = W[lane * EMB + 2 * m + 1];
        wpk[m] = (uint)bf16_rne(w0) | ((uint)bf16_rne(w1) << 16);
    }
    float bias = bv[lane];
    int stride = nblocks * 4;
    for (int row = b * 4 + wid; row < n; row += stride) {
        int s = off[row], e = off[row + 1];
        float av[4] = {0.f, 0.f, 0.f, 0.f};
        for (int p = s; p < e; p += 16) {
#pragma unroll
            for (int bb = 0; bb < 4; ++bb) {
                int idx = p + bb * 4 + g;
                int lidx = (idx < e) ? idx : (e - 1);
                int2 ed = ccv[lidx];
                float val = (idx < e) ? __int_as_float(ed.y) : 0.f;
                uint2 gx = xv2[(size_t)ed.x * 16 + q];
                av[0] = fmaf(val, __uint_as_float(gx.x << 16), av[0]);
                av[1] = fmaf(val, __uint_as_float(gx.x & 0xffff0000u), av[1]);
                av[2] = fmaf(val, __uint_as_float(gx.y << 16), av[2]);
                av[3] = fmaf(val, __uint_as_float(gx.y & 0xffff0000u), av[3]);
            }
        }
        // fold the 4 edge-groups: every lane ends with full sums for its quad
#pragma unroll
        for (int j = 0; j < 4; ++j) {
            av[j] += __shfl_xor(av[j], 16);
            av[j] += __shfl_xor(av[j], 32);
        }
        // dense: out[lane] = bias + sum_k W[lane,k]*xv[k]; xv[2m],xv[2m+1] from lane m>>1
        float acc = bias;
#pragma unroll
        for (int m = 0; m < EMB / 2; ++m) {
            uint wp = wpk[m];
            int srcl = m >> 1;
            int j0 = (m & 1) * 2;
            float x0 = __shfl(av[j0], srcl);
            float x1 = __shfl(av[j0 + 1], srcl);
            acc = fmaf(__uint_as_float(wp << 16), x0, acc);
            acc = fmaf(__uint_as_float(wp & 0xffff0000u), x1, acc);
        }
        acc = (acc > 0.f) ? acc : 0.01f * acc;
        float ss = acc * acc;
#pragma unroll
        for (int d = 32; d >= 1; d >>= 1) ss += __shfl_xor(ss, d);
        float scl = 1.0f / fmaxf(sqrtf(ss), 1e-12f);
        float outv = acc * scl;
        if (yb) yb[(size_t)row * EMB + lane] = bf16_rne(outv);
        else    yf[(size_t)row * EMB + lane] = outv;
    }
}

// ---------------- launch ----------------

extern "C" void kernel_launch(void* const* d_in, const int* in_sizes, int n_in,
                              void* d_out, int out_size, void* d_ws, size_t ws_size,
                              hipStream_t stream) {
    const float* user_emb = (const float*)d_in[0];
    const float* item_emb = (const float*)d_in[1];
    const float* Wu0 = (const float*)d_in[2];
    const float* bu0 = (const float*)d_in[3];
    const float* Wu1 = (const float*)d_in[4];
    const float* bu1 = (const float*)d_in[5];
    const float* Wi0 = (const float*)d_in[6];
    const float* bi0 = (const float*)d_in[7];
    const float* Wi1 = (const float*)d_in[8];
    const float* bi1 = (const float*)d_in[9];
    const int*   u_rows = (const int*)d_in[10];
    const int*   u_cols = (const int*)d_in[11];
    const float* u_vals = (const float*)d_in[12];
    const int*   i_rows = (const int*)d_in[13];
    const int*   i_cols = (const int*)d_in[14];
    const float* i_vals = (const float*)d_in[15];

    const int nu = in_sizes[0] / EMB;
    const int ni = in_sizes[1] / EMB;
    const int eu = in_sizes[10];
    const int ei = in_sizes[13];

    const int BU = 512, BI = 256;
    const int RPBU = (nu + BU - 1) / BU;   // 196
    const int RPBI = (ni + BI - 1) / BI;   // 196

    float* out_u = (float*)d_out;
    float* out_i = out_u + (size_t)nu * EMB;

    // workspace carve (256B aligned)
    size_t o = 0;
    char* wsb = (char*)d_ws;
    auto carve = [&](size_t bytes) -> void* {
        void* p = wsb + o;
        o += (bytes + 255) & ~(size_t)255;
        return p;
    };
    ushort* xbu0 = (ushort*)carve((size_t)nu * EMB * 2);   // bf16 cast of user_emb
    ushort* xbi0 = (ushort*)carve((size_t)ni * EMB * 2);   // bf16 cast of item_emb
    // region shared in time: binned records (CSR build) -> layer-0 bf16 outputs
    size_t binnedU_bytes = (size_t)BU * CAPB * 8;
    size_t binnedI_bytes = (size_t)BI * CAPB * 8;
    size_t xb1_bytes = ((size_t)nu + ni) * EMB * 2;
    size_t shared_bytes = binnedU_bytes + binnedI_bytes;
    if (xb1_bytes > shared_bytes) shared_bytes = xb1_bytes;
    char* regionA = (char*)carve(shared_bytes);
    int2* binnedU = (int2*)regionA;
    int2* binnedI = (int2*)(regionA + binnedU_bytes);
    ushort* xbu1 = (ushort*)regionA;                        // aliases binned (dead by then)
    ushort* xbi1 = (ushort*)(regionA + (size_t)nu * EMB * 2);
    int2* ccvU  = (int2*)carve((size_t)eu * 8);
    int2* ccvI  = (int2*)carve((size_t)ei * 8);
    int*  uoff  = (int*)carve((size_t)(nu + 1) * 4);
    int*  ioff  = (int*)carve((size_t)(ni + 1) * 4);
    int*  gcurU = (int*)carve((size_t)BU * 16 * 4);
    int*  gcurI = (int*)carve((size_t)BI * 16 * 4);
    int*  cntbU = (int*)carve((size_t)BU * 4);
    int*  ebaseU= (int*)carve((size_t)BU * 4);
    int*  cntbI = (int*)carve((size_t)BI * 4);
    int*  ebaseI= (int*)carve((size_t)BI * 4);
    (void)ws_size;

    // ---- CSR build via bucket sort ----
    init_cursors<<<(BU + BI + 255) / 256, 256, 0, stream>>>(gcurU, gcurI, BU, BI);
    bin_edges<<<(eu + CHUNK - 1) / CHUNK, 256, 0, stream>>>(
        u_rows, u_cols, u_vals, eu, BU, RPBU, gcurU, binnedU);
    bin_edges<<<(ei + CHUNK - 1) / CHUNK, 256, 0, stream>>>(
        i_rows, i_cols, i_vals, ei, BI, RPBI, gcurI, binnedI);
    scan_buckets<<<2, 1024, 0, stream>>>(gcurU, BU, cntbU, ebaseU,
                                         gcurI, BI, cntbI, ebaseI);
    finalize_csr<<<BU, 256, 0, stream>>>(binnedU, cntbU, ebaseU, RPBU, nu, ccvU, uoff);
    finalize_csr<<<BI, 256, 0, stream>>>(binnedI, cntbI, ebaseI, RPBI, ni, ccvI, ioff);

    // ---- cast input embeddings to bf16 ----
    {
        long n4u = (long)nu * EMB / 4, n4i = (long)ni * EMB / 4;
        long tot = n4u + n4i;
        cast_bf16<<<(int)((tot + 255) / 256), 256, 0, stream>>>(
            (const float4*)user_emb, xbu0, n4u, (const float4*)item_emb, xbi0, n4i);
    }

    // ---- 2 GCN layers, fused per layer; ping-pong bf16 buffers ----
    const int GBU = 1366, GBI = 682;   // 2048 blocks -> up to 8 blocks/CU resident
    // layer 0: bf16(emb) -> bf16 tmp (tmp aliases binned, which is dead now)
    spmm_dense_norm<<<GBU + GBI, 256, 0, stream>>>(
        uoff, ccvU, xbu0, Wu0, bu0, nullptr, xbu1, nu, GBU,
        ioff, ccvI, xbi0, Wi0, bi0, nullptr, xbi1, ni);
    // layer 1: bf16 tmp -> f32 out
    spmm_dense_norm<<<GBU + GBI, 256, 0, stream>>>(
        uoff, ccvU, xbu1, Wu1, bu1, out_u, nullptr, nu, GBU,
        ioff, ccvI, xbi1, Wi1, bi1, out_i, nullptr, ni);
}

// Round 8
// 678.833 us; speedup vs baseline: 1.6714x; 1.6714x over previous
//
#include <hip/hip_runtime.h>
#include <hip/hip_bf16.h>
#include <math.h>

#define EMB 64
#define CAPB 3584      // per-bucket slot capacity (mean 3125, sigma ~56 -> 8.2 sigma)
#define CHUNK 4096     // edges per bin_edges block

// ---------------- bucket-sort CSR build ----------------
// Buckets: BU=512 (user), BI=256 (item); RPB = ceil(n/B) rows per bucket (196).
// Record: int2( col | (inrow<<17), f32val )  [col<2^17, inrow<256]

__global__ void init_cursors(int* gcurU, int* gcurI, int BU, int BI) {
    int i = blockIdx.x * blockDim.x + threadIdx.x;
    if (i < BU) gcurU[i * 16] = i * CAPB;
    else if (i < BU + BI) gcurI[(i - BU) * 16] = (i - BU) * CAPB;
}

__global__ __launch_bounds__(256) void bin_edges(
    const int* __restrict__ rows, const int* __restrict__ cols,
    const float* __restrict__ vals, int nE, int B, int RPB,
    int* gcur, int2* __restrict__ binned) {
    __shared__ int cnt[512];
    __shared__ int lbase[512];
    int t = threadIdx.x;
    for (int i = t; i < B; i += 256) cnt[i] = 0;
    __syncthreads();
    int c0 = blockIdx.x * CHUNK;
    int bs[16];
#pragma unroll
    for (int j = 0; j < 16; ++j) {
        int idx = c0 + t + j * 256;
        int bsv = -1;
        if (idx < nE) {
            int row = rows[idx];
            int b = row / RPB;
            int slot = atomicAdd(&cnt[b], 1);
            bsv = (b << 16) | slot;
        }
        bs[j] = bsv;
    }
    __syncthreads();
    for (int i = t; i < B; i += 256) {
        int c = cnt[i];
        lbase[i] = c ? atomicAdd(&gcur[i * 16], c) : 0;
    }
    __syncthreads();
#pragma unroll
    for (int j = 0; j < 16; ++j) {
        int idx = c0 + t + j * 256;
        if (idx >= nE) continue;
        int bsv = bs[j];
        int b = bsv >> 16, slot = bsv & 0xFFFF;
        int row = rows[idx];          // L1/L2-hot re-read
        int col = cols[idx];
        float v = vals[idx];
        int inrow = row - b * RPB;
        int pos = lbase[b] + slot;
        if (pos < (b + 1) * CAPB)
            binned[pos] = make_int2(col | (inrow << 17), __float_as_int(v));
    }
}

// inclusive scan across a 1024-thread block; wsum is 16-int shared
__device__ __forceinline__ int block_scan_1024(int v, int* wsum) {
    int tid = threadIdx.x, lane = tid & 63, wid = tid >> 6;
    int s = v;
#pragma unroll
    for (int d = 1; d < 64; d <<= 1) {
        int t = __shfl_up(s, d);
        if (lane >= d) s += t;
    }
    if (lane == 63) wsum[wid] = s;
    __syncthreads();
    if (tid < 16) {
        int ws = wsum[tid];
#pragma unroll
        for (int d = 1; d < 16; d <<= 1) {
            int t = __shfl_up(ws, d);
            if (tid >= d) ws += t;
        }
        wsum[tid] = ws;
    }
    __syncthreads();
    int wpref = (wid > 0) ? wsum[wid - 1] : 0;
    return wpref + s;
}

// block 0: user buckets, block 1: item buckets. cntb[b], ebase[b] (exclusive)
__global__ void scan_buckets(const int* __restrict__ gcurU, int BU, int* cntbU, int* ebaseU,
                             const int* __restrict__ gcurI, int BI, int* cntbI, int* ebaseI) {
    __shared__ int wsum[16];
    const int* gcur; int B; int* cntb; int* ebase;
    if (blockIdx.x == 0) { gcur = gcurU; B = BU; cntb = cntbU; ebase = ebaseU; }
    else { gcur = gcurI; B = BI; cntb = cntbI; ebase = ebaseI; }
    int t = threadIdx.x;
    int v = 0;
    if (t < B) {
        v = gcur[t * 16] - t * CAPB;
        if (v < 0) v = 0;
        if (v > CAPB) v = CAPB;
    }
    int incl = block_scan_1024(v, wsum);
    if (t < B) { cntb[t] = v; ebase[t] = incl - v; }
}

// one workgroup per bucket: stage records in LDS, count rows, scan, emit CSR
__global__ __launch_bounds__(256) void finalize_csr(
    const int2* __restrict__ binned, const int* __restrict__ cntb,
    const int* __restrict__ ebase, int RPB, int n,
    int2* __restrict__ ccv, int* __restrict__ off) {
    __shared__ int2 rec[CAPB];
    __shared__ int cnt_r[256];
    __shared__ int excl[257];
    __shared__ int curs[256];
    int b = blockIdx.x;
    int t = threadIdx.x;
    int r0 = b * RPB;
    int nrows = n - r0; if (nrows > RPB) nrows = RPB;
    if (nrows <= 0) return;
    int cnt = cntb[b];
    int eb  = ebase[b];
    const int2* src = binned + (size_t)b * CAPB;
    cnt_r[t] = 0;
    __syncthreads();
    for (int p = t; p < cnt; p += 256) {
        int2 r = src[p];
        rec[p] = r;
        atomicAdd(&cnt_r[(r.x >> 17) & 0xFF], 1);
    }
    __syncthreads();
    // exclusive scan of 256 counters: wave 0, 4 segments of 64 with carry
    if (t < 64) {
        int carry = 0;
#pragma unroll
        for (int seg = 0; seg < 4; ++seg) {
            int i = seg * 64 + t;
            int v = cnt_r[i];
            int s = v;
#pragma unroll
            for (int d = 1; d < 64; d <<= 1) {
                int u2 = __shfl_up(s, d);
                if (t >= d) s += u2;
            }
            excl[i] = carry + s - v;
            carry += __shfl(s, 63);
        }
        if (t == 0) excl[256] = carry;
    }
    __syncthreads();
    curs[t] = excl[t];
    if (t < nrows) off[r0 + t] = eb + excl[t];
    if (t == 0 && r0 + nrows == n) off[n] = eb + cnt;
    __syncthreads();
    for (int p = t; p < cnt; p += 256) {
        int2 r = rec[p];
        int inrow = (r.x >> 17) & 0xFF;
        int slot = atomicAdd(&curs[inrow], 1);
        ccv[eb + slot] = make_int2(r.x & 0x1FFFF, r.y);
    }
}

// ---------------- f32 -> bf16 cast (RNE), vectorized ----------------

__device__ __forceinline__ ushort bf16_rne(float f) {
    uint u = __float_as_uint(f);
    return (ushort)((u + 0x7fffu + ((u >> 16) & 1u)) >> 16);
}

__global__ void cast_bf16(const float4* __restrict__ au, ushort* __restrict__ ou, long n4u,
                          const float4* __restrict__ ai, ushort* __restrict__ oi, long n4i) {
    long i = (long)blockIdx.x * blockDim.x + threadIdx.x;
    long tot = n4u + n4i;
    if (i >= tot) return;
    const float4* a; ushort* o; long j;
    if (i < n4u) { a = au; o = ou; j = i; }
    else { a = ai; o = oi; j = i - n4u; }
    float4 v = a[j];
    ushort4 r;
    r.x = bf16_rne(v.x); r.y = bf16_rne(v.y); r.z = bf16_rne(v.z); r.w = bf16_rne(v.w);
    *(ushort4*)(o + j * 4) = r;
}

// ---------------- fused SPMM + dense(x@W^T+b) + leaky_relu + L2 norm ----------------
// Wave split into 4 groups of 16 lanes; each group gathers ONE edge's 64-feature bf16
// row as uint2 (8B/lane) -> one VMEM instruction moves 4 edges (512B).
// lane = q + 16*g: q = feature quad, g = edge group.
// W lives in LDS as bf16x2 packed, layout [m][lane] (transposed -> 2-way bank = free).
// No W in registers => ~55 VGPRs => 6 blocks/CU at launch_bounds(256,6), NO spill.
// x and y MUST be distinct buffers (gather reads random rows).

__global__ __launch_bounds__(256, 6) void spmm_dense_norm(
    const int* __restrict__ uoff, const int2* __restrict__ ccvU,
    const ushort* __restrict__ xu, const float* __restrict__ Wu, const float* __restrict__ bu,
    float* __restrict__ yfu, ushort* __restrict__ ybu, int nu, int gbu,
    const int* __restrict__ ioff, const int2* __restrict__ ccvI,
    const ushort* __restrict__ xi, const float* __restrict__ Wi, const float* __restrict__ bi,
    float* __restrict__ yfi, ushort* __restrict__ ybi, int ni) {
    __shared__ uint wlds[(EMB / 2) * EMB];   // 8 KB: wlds[m*64+lane] = pack(W[lane][2m], W[lane][2m+1])
    int lane = threadIdx.x & 63, wid = threadIdx.x >> 6;
    int q = lane & 15, g = lane >> 4;
    const int* off; const int2* ccv; const ushort* x; const float* W; const float* bv;
    float* yf; ushort* yb; int n; int b; int nblocks;
    if ((int)blockIdx.x < gbu) {
        off = uoff; ccv = ccvU; x = xu; W = Wu; bv = bu; yf = yfu; yb = ybu; n = nu;
        b = blockIdx.x; nblocks = gbu;
    } else {
        off = ioff; ccv = ccvI; x = xi; W = Wi; bv = bi; yf = yfi; yb = ybi; n = ni;
        b = blockIdx.x - gbu; nblocks = gridDim.x - gbu;
    }
    // cooperative W load: idx = m*64 + l
    for (int idx = threadIdx.x; idx < (EMB / 2) * EMB; idx += 256) {
        int m = idx >> 6, l = idx & 63;
        float w0 = W[l * EMB + 2 * m];
        float w1 = W[l * EMB + 2 * m + 1];
        wlds[idx] = (uint)bf16_rne(w0) | ((uint)bf16_rne(w1) << 16);
    }
    float bias = bv[lane];
    __syncthreads();
    const uint2* xv2 = (const uint2*)x;
    int stride = nblocks * 4;
    for (int row = b * 4 + wid; row < n; row += stride) {
        int s = off[row], e = off[row + 1];
        float av[4] = {0.f, 0.f, 0.f, 0.f};
        for (int p = s; p < e; p += 16) {
#pragma unroll
            for (int bb = 0; bb < 4; ++bb) {
                int idx = p + bb * 4 + g;
                int lidx = (idx < e) ? idx : (e - 1);
                int2 ed = ccv[lidx];
                float val = (idx < e) ? __int_as_float(ed.y) : 0.f;
                uint2 gx = xv2[(size_t)ed.x * 16 + q];
                av[0] = fmaf(val, __uint_as_float(gx.x << 16), av[0]);
                av[1] = fmaf(val, __uint_as_float(gx.x & 0xffff0000u), av[1]);
                av[2] = fmaf(val, __uint_as_float(gx.y << 16), av[2]);
                av[3] = fmaf(val, __uint_as_float(gx.y & 0xffff0000u), av[3]);
            }
        }
        // fold the 4 edge-groups: every lane ends with full sums for its quad
#pragma unroll
        for (int j = 0; j < 4; ++j) {
            av[j] += __shfl_xor(av[j], 16);
            av[j] += __shfl_xor(av[j], 32);
        }
        // dense: out[lane] = bias + sum_k W[lane,k]*xv[k]; xv[2m],xv[2m+1] from lane m>>1
        float acc = bias;
#pragma unroll
        for (int m = 0; m < EMB / 2; ++m) {
            uint wp = wlds[(m << 6) | lane];
            int srcl = m >> 1;
            int j0 = (m & 1) * 2;
            float x0 = __shfl(av[j0], srcl);
            float x1 = __shfl(av[j0 + 1], srcl);
            acc = fmaf(__uint_as_float(wp << 16), x0, acc);
            acc = fmaf(__uint_as_float(wp & 0xffff0000u), x1, acc);
        }
        acc = (acc > 0.f) ? acc : 0.01f * acc;
        float ss = acc * acc;
#pragma unroll
        for (int d = 32; d >= 1; d >>= 1) ss += __shfl_xor(ss, d);
        float scl = 1.0f / fmaxf(sqrtf(ss), 1e-12f);
        float outv = acc * scl;
        if (yb) yb[(size_t)row * EMB + lane] = bf16_rne(outv);
        else    yf[(size_t)row * EMB + lane] = outv;
    }
}

// ---------------- launch ----------------

extern "C" void kernel_launch(void* const* d_in, const int* in_sizes, int n_in,
                              void* d_out, int out_size, void* d_ws, size_t ws_size,
                              hipStream_t stream) {
    const float* user_emb = (const float*)d_in[0];
    const float* item_emb = (const float*)d_in[1];
    const float* Wu0 = (const float*)d_in[2];
    const float* bu0 = (const float*)d_in[3];
    const float* Wu1 = (const float*)d_in[4];
    const float* bu1 = (const float*)d_in[5];
    const float* Wi0 = (const float*)d_in[6];
    const float* bi0 = (const float*)d_in[7];
    const float* Wi1 = (const float*)d_in[8];
    const float* bi1 = (const float*)d_in[9];
    const int*   u_rows = (const int*)d_in[10];
    const int*   u_cols = (const int*)d_in[11];
    const float* u_vals = (const float*)d_in[12];
    const int*   i_rows = (const int*)d_in[13];
    const int*   i_cols = (const int*)d_in[14];
    const float* i_vals = (const float*)d_in[15];

    const int nu = in_sizes[0] / EMB;
    const int ni = in_sizes[1] / EMB;
    const int eu = in_sizes[10];
    const int ei = in_sizes[13];

    const int BU = 512, BI = 256;
    const int RPBU = (nu + BU - 1) / BU;   // 196
    const int RPBI = (ni + BI - 1) / BI;   // 196

    float* out_u = (float*)d_out;
    float* out_i = out_u + (size_t)nu * EMB;

    // workspace carve (256B aligned)
    size_t o = 0;
    char* wsb = (char*)d_ws;
    auto carve = [&](size_t bytes) -> void* {
        void* p = wsb + o;
        o += (bytes + 255) & ~(size_t)255;
        return p;
    };
    ushort* xbu0 = (ushort*)carve((size_t)nu * EMB * 2);   // bf16 cast of user_emb
    ushort* xbi0 = (ushort*)carve((size_t)ni * EMB * 2);   // bf16 cast of item_emb
    // region shared in time: binned records (CSR build) -> layer-0 bf16 outputs
    size_t binnedU_bytes = (size_t)BU * CAPB * 8;
    size_t binnedI_bytes = (size_t)BI * CAPB * 8;
    size_t xb1_bytes = ((size_t)nu + ni) * EMB * 2;
    size_t shared_bytes = binnedU_bytes + binnedI_bytes;
    if (xb1_bytes > shared_bytes) shared_bytes = xb1_bytes;
    char* regionA = (char*)carve(shared_bytes);
    int2* binnedU = (int2*)regionA;
    int2* binnedI = (int2*)(regionA + binnedU_bytes);
    ushort* xbu1 = (ushort*)regionA;                        // aliases binned (dead by then)
    ushort* xbi1 = (ushort*)(regionA + (size_t)nu * EMB * 2);
    int2* ccvU  = (int2*)carve((size_t)eu * 8);
    int2* ccvI  = (int2*)carve((size_t)ei * 8);
    int*  uoff  = (int*)carve((size_t)(nu + 1) * 4);
    int*  ioff  = (int*)carve((size_t)(ni + 1) * 4);
    int*  gcurU = (int*)carve((size_t)BU * 16 * 4);
    int*  gcurI = (int*)carve((size_t)BI * 16 * 4);
    int*  cntbU = (int*)carve((size_t)BU * 4);
    int*  ebaseU= (int*)carve((size_t)BU * 4);
    int*  cntbI = (int*)carve((size_t)BI * 4);
    int*  ebaseI= (int*)carve((size_t)BI * 4);
    (void)ws_size;

    // ---- CSR build via bucket sort ----
    init_cursors<<<(BU + BI + 255) / 256, 256, 0, stream>>>(gcurU, gcurI, BU, BI);
    bin_edges<<<(eu + CHUNK - 1) / CHUNK, 256, 0, stream>>>(
        u_rows, u_cols, u_vals, eu, BU, RPBU, gcurU, binnedU);
    bin_edges<<<(ei + CHUNK - 1) / CHUNK, 256, 0, stream>>>(
        i_rows, i_cols, i_vals, ei, BI, RPBI, gcurI, binnedI);
    scan_buckets<<<2, 1024, 0, stream>>>(gcurU, BU, cntbU, ebaseU,
                                         gcurI, BI, cntbI, ebaseI);
    finalize_csr<<<BU, 256, 0, stream>>>(binnedU, cntbU, ebaseU, RPBU, nu, ccvU, uoff);
    finalize_csr<<<BI, 256, 0, stream>>>(binnedI, cntbI, ebaseI, RPBI, ni, ccvI, ioff);

    // ---- cast input embeddings to bf16 ----
    {
        long n4u = (long)nu * EMB / 4, n4i = (long)ni * EMB / 4;
        long tot = n4u + n4i;
        cast_bf16<<<(int)((tot + 255) / 256), 256, 0, stream>>>(
            (const float4*)user_emb, xbu0, n4u, (const float4*)item_emb, xbi0, n4i);
    }

    // ---- 2 GCN layers, fused per layer; ping-pong bf16 buffers ----
    const int GBU = 1024, GBI = 512;   // 1536 blocks = 6 blocks/CU resident, 2:1 work split
    // layer 0: bf16(emb) -> bf16 tmp (tmp aliases binned, which is dead now)
    spmm_dense_norm<<<GBU + GBI, 256, 0, stream>>>(
        uoff, ccvU, xbu0, Wu0, bu0, nullptr, xbu1, nu, GBU,
        ioff, ccvI, xbi0, Wi0, bi0, nullptr, xbi1, ni);
    // layer 1: bf16 tmp -> f32 out
    spmm_dense_norm<<<GBU + GBI, 256, 0, stream>>>(
        uoff, ccvU, xbu1, Wu1, bu1, out_u, nullptr, nu, GBU,
        ioff, ccvI, xbi1, Wi1, bi1, out_i, nullptr, ni);
}

// Round 9
// 408.924 us; speedup vs baseline: 2.7746x; 1.6600x over previous
//
#include <hip/hip_runtime.h>
#include <hip/hip_bf16.h>
#include <math.h>

#define EMB 64
#define CAPB 3584      // per-bucket slot capacity (mean 3125, sigma ~56 -> 8.2 sigma)
#define CHUNK 4096     // edges per bin_edges block

typedef __attribute__((ext_vector_type(8))) short bf16x8;
typedef __attribute__((ext_vector_type(4))) float f32x4;

// ---------------- bucket-sort CSR build ----------------
// Buckets: BU=512 (user), BI=256 (item); RPB = ceil(n/B) rows per bucket (196).
// Record: int2( col | (inrow<<17), f32val )  [col<2^17, inrow<256]

__global__ void init_cursors(int* gcurU, int* gcurI, int BU, int BI) {
    int i = blockIdx.x * blockDim.x + threadIdx.x;
    if (i < BU) gcurU[i * 16] = i * CAPB;
    else if (i < BU + BI) gcurI[(i - BU) * 16] = (i - BU) * CAPB;
}

__global__ __launch_bounds__(256) void bin_edges(
    const int* __restrict__ rows, const int* __restrict__ cols,
    const float* __restrict__ vals, int nE, int B, int RPB,
    int* gcur, int2* __restrict__ binned) {
    __shared__ int cnt[512];
    __shared__ int lbase[512];
    int t = threadIdx.x;
    for (int i = t; i < B; i += 256) cnt[i] = 0;
    __syncthreads();
    int c0 = blockIdx.x * CHUNK;
    int bs[16];
#pragma unroll
    for (int j = 0; j < 16; ++j) {
        int idx = c0 + t + j * 256;
        int bsv = -1;
        if (idx < nE) {
            int row = rows[idx];
            int b = row / RPB;
            int slot = atomicAdd(&cnt[b], 1);
            bsv = (b << 16) | slot;
        }
        bs[j] = bsv;
    }
    __syncthreads();
    for (int i = t; i < B; i += 256) {
        int c = cnt[i];
        lbase[i] = c ? atomicAdd(&gcur[i * 16], c) : 0;
    }
    __syncthreads();
#pragma unroll
    for (int j = 0; j < 16; ++j) {
        int idx = c0 + t + j * 256;
        if (idx >= nE) continue;
        int bsv = bs[j];
        int b = bsv >> 16, slot = bsv & 0xFFFF;
        int row = rows[idx];          // L1/L2-hot re-read
        int col = cols[idx];
        float v = vals[idx];
        int inrow = row - b * RPB;
        int pos = lbase[b] + slot;
        if (pos < (b + 1) * CAPB)
            binned[pos] = make_int2(col | (inrow << 17), __float_as_int(v));
    }
}

// inclusive scan across a 1024-thread block; wsum is 16-int shared
__device__ __forceinline__ int block_scan_1024(int v, int* wsum) {
    int tid = threadIdx.x, lane = tid & 63, wid = tid >> 6;
    int s = v;
#pragma unroll
    for (int d = 1; d < 64; d <<= 1) {
        int t = __shfl_up(s, d);
        if (lane >= d) s += t;
    }
    if (lane == 63) wsum[wid] = s;
    __syncthreads();
    if (tid < 16) {
        int ws = wsum[tid];
#pragma unroll
        for (int d = 1; d < 16; d <<= 1) {
            int t = __shfl_up(ws, d);
            if (tid >= d) ws += t;
        }
        wsum[tid] = ws;
    }
    __syncthreads();
    int wpref = (wid > 0) ? wsum[wid - 1] : 0;
    return wpref + s;
}

// block 0: user buckets, block 1: item buckets. cntb[b], ebase[b] (exclusive)
__global__ void scan_buckets(const int* __restrict__ gcurU, int BU, int* cntbU, int* ebaseU,
                             const int* __restrict__ gcurI, int BI, int* cntbI, int* ebaseI) {
    __shared__ int wsum[16];
    const int* gcur; int B; int* cntb; int* ebase;
    if (blockIdx.x == 0) { gcur = gcurU; B = BU; cntb = cntbU; ebase = ebaseU; }
    else { gcur = gcurI; B = BI; cntb = cntbI; ebase = ebaseI; }
    int t = threadIdx.x;
    int v = 0;
    if (t < B) {
        v = gcur[t * 16] - t * CAPB;
        if (v < 0) v = 0;
        if (v > CAPB) v = CAPB;
    }
    int incl = block_scan_1024(v, wsum);
    if (t < B) { cntb[t] = v; ebase[t] = incl - v; }
}

// one workgroup per bucket: stage records in LDS, count rows, scan, emit CSR
__global__ __launch_bounds__(256) void finalize_csr(
    const int2* __restrict__ binned, const int* __restrict__ cntb,
    const int* __restrict__ ebase, int RPB, int n,
    int2* __restrict__ ccv, int* __restrict__ off) {
    __shared__ int2 rec[CAPB];
    __shared__ int cnt_r[256];
    __shared__ int excl[257];
    __shared__ int curs[256];
    int b = blockIdx.x;
    int t = threadIdx.x;
    int r0 = b * RPB;
    int nrows = n - r0; if (nrows > RPB) nrows = RPB;
    if (nrows <= 0) return;
    int cnt = cntb[b];
    int eb  = ebase[b];
    const int2* src = binned + (size_t)b * CAPB;
    cnt_r[t] = 0;
    __syncthreads();
    for (int p = t; p < cnt; p += 256) {
        int2 r = src[p];
        rec[p] = r;
        atomicAdd(&cnt_r[(r.x >> 17) & 0xFF], 1);
    }
    __syncthreads();
    // exclusive scan of 256 counters: wave 0, 4 segments of 64 with carry
    if (t < 64) {
        int carry = 0;
#pragma unroll
        for (int seg = 0; seg < 4; ++seg) {
            int i = seg * 64 + t;
            int v = cnt_r[i];
            int s = v;
#pragma unroll
            for (int d = 1; d < 64; d <<= 1) {
                int u2 = __shfl_up(s, d);
                if (t >= d) s += u2;
            }
            excl[i] = carry + s - v;
            carry += __shfl(s, 63);
        }
        if (t == 0) excl[256] = carry;
    }
    __syncthreads();
    curs[t] = excl[t];
    if (t < nrows) off[r0 + t] = eb + excl[t];
    if (t == 0 && r0 + nrows == n) off[n] = eb + cnt;
    __syncthreads();
    for (int p = t; p < cnt; p += 256) {
        int2 r = rec[p];
        int inrow = (r.x >> 17) & 0xFF;
        int slot = atomicAdd(&curs[inrow], 1);
        ccv[eb + slot] = make_int2(r.x & 0x1FFFF, r.y);
    }
}

// ---------------- f32 -> bf16 cast (RNE), vectorized ----------------

__device__ __forceinline__ ushort bf16_rne(float f) {
    uint u = __float_as_uint(f);
    return (ushort)((u + 0x7fffu + ((u >> 16) & 1u)) >> 16);
}

__global__ void cast_bf16(const float4* __restrict__ au, ushort* __restrict__ ou, long n4u,
                          const float4* __restrict__ ai, ushort* __restrict__ oi, long n4i) {
    long i = (long)blockIdx.x * blockDim.x + threadIdx.x;
    long tot = n4u + n4i;
    if (i >= tot) return;
    const float4* a; ushort* o; long j;
    if (i < n4u) { a = au; o = ou; j = i; }
    else { a = ai; o = oi; j = i - n4u; }
    float4 v = a[j];
    ushort4 r;
    r.x = bf16_rne(v.x); r.y = bf16_rne(v.y); r.z = bf16_rne(v.z); r.w = bf16_rne(v.w);
    *(ushort4*)(o + j * 4) = r;
}

// ---------------- fused SPMM + MFMA dense + leaky_relu + L2 norm ----------------
// Block = 4 waves, 64-row tile; wave owns 16 rows.
// Gather (round-6 proven): wave split into 4 groups of 16 lanes; each group gathers
// one edge's 64-feat bf16 row as uint2 (8B/lane); 16-edge batches. Fold via shfl_xor.
// Each gathered row is packed bf16 and written to a per-wave LDS X tile [16][72]
// (pad 64->72 elts: 2-way banks = free). W staged once in LDS [64][72] bf16.
// Dense: X(16x64) @ W^T via 8x mfma_f32_16x16x32_bf16; B-frag = W[n][k] contiguous
// -> single 16B LDS read per frag. C/D layout (verified): col=lane&15,
// row=(lane>>4)*4+reg. Norm: 4-step shfl_xor butterfly over col lanes.
// x and y MUST be distinct buffers (gather reads random rows).

__global__ __launch_bounds__(256, 4) void spmm_mfma(
    const int* __restrict__ uoff, const int2* __restrict__ ccvU,
    const ushort* __restrict__ xu, const float* __restrict__ Wu, const float* __restrict__ bu,
    float* __restrict__ yfu, ushort* __restrict__ ybu, int nu, int gbu,
    const int* __restrict__ ioff, const int2* __restrict__ ccvI,
    const ushort* __restrict__ xi, const float* __restrict__ Wi, const float* __restrict__ bi,
    float* __restrict__ yfi, ushort* __restrict__ ybi, int ni) {
    __shared__ ushort wt[64 * 72];       // W row-major bf16, rows padded to 72
    __shared__ ushort xt[4 * 16 * 72];   // per-wave X tiles
    int tid = threadIdx.x;
    int lane = tid & 63, wid = tid >> 6;
    int q = lane & 15, g = lane >> 4;
    const int* off; const int2* ccv; const ushort* x; const float* W; const float* bv;
    float* yf; ushort* yb; int n; int b; int nblocks;
    if ((int)blockIdx.x < gbu) {
        off = uoff; ccv = ccvU; x = xu; W = Wu; bv = bu; yf = yfu; yb = ybu; n = nu;
        b = blockIdx.x; nblocks = gbu;
    } else {
        off = ioff; ccv = ccvI; x = xi; W = Wi; bv = bi; yf = yfi; yb = ybi; n = ni;
        b = blockIdx.x - gbu; nblocks = gridDim.x - gbu;
    }
    // stage W: coalesced read, bf16 into padded LDS
    for (int idx = tid; idx < EMB * EMB; idx += 256) {
        int r = idx >> 6, c = idx & 63;
        wt[r * 72 + c] = bf16_rne(W[idx]);
    }
    float bias[4];
#pragma unroll
    for (int t = 0; t < 4; ++t) bias[t] = bv[16 * t + q];
    __syncthreads();

    const uint2* xv2 = (const uint2*)x;
    ushort* xw = xt + wid * (16 * 72);
    int ntiles = (n + 63) >> 6;
    for (int tile = b; tile < ntiles; tile += nblocks) {
        int rowW = (tile << 6) + wid * 16;   // wave's first row
        // ---- gather 16 rows into LDS X tile ----
        for (int rr = 0; rr < 16; ++rr) {
            int row = rowW + rr;
            float av[4] = {0.f, 0.f, 0.f, 0.f};
            if (row < n) {
                int s = off[row], e = off[row + 1];
                for (int p = s; p < e; p += 16) {
#pragma unroll
                    for (int bb = 0; bb < 4; ++bb) {
                        int idx = p + bb * 4 + g;
                        int lidx = (idx < e) ? idx : (e - 1);
                        int2 ed = ccv[lidx];
                        float val = (idx < e) ? __int_as_float(ed.y) : 0.f;
                        uint2 gx = xv2[(size_t)ed.x * 16 + q];
                        av[0] = fmaf(val, __uint_as_float(gx.x << 16), av[0]);
                        av[1] = fmaf(val, __uint_as_float(gx.x & 0xffff0000u), av[1]);
                        av[2] = fmaf(val, __uint_as_float(gx.y << 16), av[2]);
                        av[3] = fmaf(val, __uint_as_float(gx.y & 0xffff0000u), av[3]);
                    }
                }
#pragma unroll
                for (int j = 0; j < 4; ++j) {
                    av[j] += __shfl_xor(av[j], 16);
                    av[j] += __shfl_xor(av[j], 32);
                }
            }
            if (g == 0) {   // 16 lanes write the packed row (128B, conflict-free)
                uint p0 = (uint)bf16_rne(av[0]) | ((uint)bf16_rne(av[1]) << 16);
                uint p1 = (uint)bf16_rne(av[2]) | ((uint)bf16_rne(av[3]) << 16);
                *(uint2*)(xw + rr * 72 + q * 4) = make_uint2(p0, p1);
            }
        }
        __syncthreads();   // X tiles visible (cross-lane)

        // ---- dense: D(16x64) = X @ W^T, 2 K-steps x 4 N-tiles ----
        f32x4 ac0 = {0.f, 0.f, 0.f, 0.f}, ac1 = ac0, ac2 = ac0, ac3 = ac0;
#pragma unroll
        for (int ks = 0; ks < 2; ++ks) {
            bf16x8 af = *(const bf16x8*)(xw + q * 72 + g * 8 + ks * 32);
            bf16x8 b0 = *(const bf16x8*)(wt + (q +  0) * 72 + g * 8 + ks * 32);
            bf16x8 b1 = *(const bf16x8*)(wt + (q + 16) * 72 + g * 8 + ks * 32);
            bf16x8 b2 = *(const bf16x8*)(wt + (q + 32) * 72 + g * 8 + ks * 32);
            bf16x8 b3 = *(const bf16x8*)(wt + (q + 48) * 72 + g * 8 + ks * 32);
            ac0 = __builtin_amdgcn_mfma_f32_16x16x32_bf16(af, b0, ac0, 0, 0, 0);
            ac1 = __builtin_amdgcn_mfma_f32_16x16x32_bf16(af, b1, ac1, 0, 0, 0);
            ac2 = __builtin_amdgcn_mfma_f32_16x16x32_bf16(af, b2, ac2, 0, 0, 0);
            ac3 = __builtin_amdgcn_mfma_f32_16x16x32_bf16(af, b3, ac3, 0, 0, 0);
        }
        __syncthreads();   // safe to overwrite X next iteration

        // ---- bias + leaky_relu + L2 norm + store ----
        // lane holds D[row=g*4+r][col=q+16t] for t,r in 0..3
        float dv[4][4];
        float ss[4] = {0.f, 0.f, 0.f, 0.f};
#pragma unroll
        for (int t = 0; t < 4; ++t) {
            f32x4 a = (t == 0) ? ac0 : (t == 1) ? ac1 : (t == 2) ? ac2 : ac3;
#pragma unroll
            for (int r = 0; r < 4; ++r) {
                float d = a[r] + bias[t];
                d = (d > 0.f) ? d : 0.01f * d;
                dv[t][r] = d;
                ss[r] = fmaf(d, d, ss[r]);
            }
        }
#pragma unroll
        for (int r = 0; r < 4; ++r) {
            float s2 = ss[r];
            s2 += __shfl_xor(s2, 1);
            s2 += __shfl_xor(s2, 2);
            s2 += __shfl_xor(s2, 4);
            s2 += __shfl_xor(s2, 8);
            float scl = 1.0f / fmaxf(sqrtf(s2), 1e-12f);
            int orow = rowW + g * 4 + r;
            if (orow < n) {
#pragma unroll
                for (int t = 0; t < 4; ++t) {
                    float outv = dv[t][r] * scl;
                    size_t cidx = (size_t)orow * EMB + 16 * t + q;
                    if (yb) yb[cidx] = bf16_rne(outv);
                    else    yf[cidx] = outv;
                }
            }
        }
    }
}

// ---------------- launch ----------------

extern "C" void kernel_launch(void* const* d_in, const int* in_sizes, int n_in,
                              void* d_out, int out_size, void* d_ws, size_t ws_size,
                              hipStream_t stream) {
    const float* user_emb = (const float*)d_in[0];
    const float* item_emb = (const float*)d_in[1];
    const float* Wu0 = (const float*)d_in[2];
    const float* bu0 = (const float*)d_in[3];
    const float* Wu1 = (const float*)d_in[4];
    const float* bu1 = (const float*)d_in[5];
    const float* Wi0 = (const float*)d_in[6];
    const float* bi0 = (const float*)d_in[7];
    const float* Wi1 = (const float*)d_in[8];
    const float* bi1 = (const float*)d_in[9];
    const int*   u_rows = (const int*)d_in[10];
    const int*   u_cols = (const int*)d_in[11];
    const float* u_vals = (const float*)d_in[12];
    const int*   i_rows = (const int*)d_in[13];
    const int*   i_cols = (const int*)d_in[14];
    const float* i_vals = (const float*)d_in[15];

    const int nu = in_sizes[0] / EMB;
    const int ni = in_sizes[1] / EMB;
    const int eu = in_sizes[10];
    const int ei = in_sizes[13];

    const int BU = 512, BI = 256;
    const int RPBU = (nu + BU - 1) / BU;   // 196
    const int RPBI = (ni + BI - 1) / BI;   // 196

    float* out_u = (float*)d_out;
    float* out_i = out_u + (size_t)nu * EMB;

    // workspace carve (256B aligned)
    size_t o = 0;
    char* wsb = (char*)d_ws;
    auto carve = [&](size_t bytes) -> void* {
        void* p = wsb + o;
        o += (bytes + 255) & ~(size_t)255;
        return p;
    };
    ushort* xbu0 = (ushort*)carve((size_t)nu * EMB * 2);   // bf16 cast of user_emb
    ushort* xbi0 = (ushort*)carve((size_t)ni * EMB * 2);   // bf16 cast of item_emb
    // region shared in time: binned records (CSR build) -> layer-0 bf16 outputs
    size_t binnedU_bytes = (size_t)BU * CAPB * 8;
    size_t binnedI_bytes = (size_t)BI * CAPB * 8;
    size_t xb1_bytes = ((size_t)nu + ni) * EMB * 2;
    size_t shared_bytes = binnedU_bytes + binnedI_bytes;
    if (xb1_bytes > shared_bytes) shared_bytes = xb1_bytes;
    char* regionA = (char*)carve(shared_bytes);
    int2* binnedU = (int2*)regionA;
    int2* binnedI = (int2*)(regionA + binnedU_bytes);
    ushort* xbu1 = (ushort*)regionA;                        // aliases binned (dead by then)
    ushort* xbi1 = (ushort*)(regionA + (size_t)nu * EMB * 2);
    int2* ccvU  = (int2*)carve((size_t)eu * 8);
    int2* ccvI  = (int2*)carve((size_t)ei * 8);
    int*  uoff  = (int*)carve((size_t)(nu + 1) * 4);
    int*  ioff  = (int*)carve((size_t)(ni + 1) * 4);
    int*  gcurU = (int*)carve((size_t)BU * 16 * 4);
    int*  gcurI = (int*)carve((size_t)BI * 16 * 4);
    int*  cntbU = (int*)carve((size_t)BU * 4);
    int*  ebaseU= (int*)carve((size_t)BU * 4);
    int*  cntbI = (int*)carve((size_t)BI * 4);
    int*  ebaseI= (int*)carve((size_t)BI * 4);
    (void)ws_size;

    // ---- CSR build via bucket sort ----
    init_cursors<<<(BU + BI + 255) / 256, 256, 0, stream>>>(gcurU, gcurI, BU, BI);
    bin_edges<<<(eu + CHUNK - 1) / CHUNK, 256, 0, stream>>>(
        u_rows, u_cols, u_vals, eu, BU, RPBU, gcurU, binnedU);
    bin_edges<<<(ei + CHUNK - 1) / CHUNK, 256, 0, stream>>>(
        i_rows, i_cols, i_vals, ei, BI, RPBI, gcurI, binnedI);
    scan_buckets<<<2, 1024, 0, stream>>>(gcurU, BU, cntbU, ebaseU,
                                         gcurI, BI, cntbI, ebaseI);
    finalize_csr<<<BU, 256, 0, stream>>>(binnedU, cntbU, ebaseU, RPBU, nu, ccvU, uoff);
    finalize_csr<<<BI, 256, 0, stream>>>(binnedI, cntbI, ebaseI, RPBI, ni, ccvI, ioff);

    // ---- cast input embeddings to bf16 ----
    {
        long n4u = (long)nu * EMB / 4, n4i = (long)ni * EMB / 4;
        long tot = n4u + n4i;
        cast_bf16<<<(int)((tot + 255) / 256), 256, 0, stream>>>(
            (const float4*)user_emb, xbu0, n4u, (const float4*)item_emb, xbi0, n4i);
    }

    // ---- 2 GCN layers, fused per layer; ping-pong bf16 buffers ----
    const int GBU = 683, GBI = 341;   // 1024 blocks = 4 blocks/CU (round-6 regime)
    // layer 0: bf16(emb) -> bf16 tmp (tmp aliases binned, which is dead now)
    spmm_mfma<<<GBU + GBI, 256, 0, stream>>>(
        uoff, ccvU, xbu0, Wu0, bu0, nullptr, xbu1, nu, GBU,
        ioff, ccvI, xbi0, Wi0, bi0, nullptr, xbi1, ni);
    // layer 1: bf16 tmp -> f32 out
    spmm_mfma<<<GBU + GBI, 256, 0, stream>>>(
        uoff, ccvU, xbu1, Wu1, bu1, out_u, nullptr, nu, GBU,
        ioff, ccvI, xbi1, Wi1, bi1, out_i, nullptr, ni);
}

// Round 10
// 241.986 us; speedup vs baseline: 4.6887x; 1.6899x over previous
//
#include <hip/hip_runtime.h>
#include <hip/hip_bf16.h>
#include <math.h>

#define EMB 64
#define CAPB 3584      // per-bucket slot capacity (mean 3125, sigma ~56 -> 8.2 sigma)
#define CHUNK 4096     // edges per bin_edges block

typedef __attribute__((ext_vector_type(8))) short bf16x8;
typedef __attribute__((ext_vector_type(4))) float f32x4;

// ---------------- bucket-sort CSR build ----------------
// Buckets: BU=512 (user), BI=256 (item); RPB = ceil(n/B) rows per bucket (196).
// Record: int2( col | (inrow<<17), f32val )  [col<2^17, inrow<256]

__global__ void init_cursors(int* gcurU, int* gcurI, int BU, int BI) {
    int i = blockIdx.x * blockDim.x + threadIdx.x;
    if (i < BU) gcurU[i * 16] = i * CAPB;
    else if (i < BU + BI) gcurI[(i - BU) * 16] = (i - BU) * CAPB;
}

__global__ __launch_bounds__(256) void bin_edges(
    const int* __restrict__ rows, const int* __restrict__ cols,
    const float* __restrict__ vals, int nE, int B, int RPB,
    int* gcur, int2* __restrict__ binned) {
    __shared__ int cnt[512];
    __shared__ int lbase[512];
    int t = threadIdx.x;
    for (int i = t; i < B; i += 256) cnt[i] = 0;
    __syncthreads();
    int c0 = blockIdx.x * CHUNK;
    int bs[16];
#pragma unroll
    for (int j = 0; j < 16; ++j) {
        int idx = c0 + t + j * 256;
        int bsv = -1;
        if (idx < nE) {
            int row = rows[idx];
            int b = row / RPB;
            int slot = atomicAdd(&cnt[b], 1);
            bsv = (b << 16) | slot;
        }
        bs[j] = bsv;
    }
    __syncthreads();
    for (int i = t; i < B; i += 256) {
        int c = cnt[i];
        lbase[i] = c ? atomicAdd(&gcur[i * 16], c) : 0;
    }
    __syncthreads();
#pragma unroll
    for (int j = 0; j < 16; ++j) {
        int idx = c0 + t + j * 256;
        if (idx >= nE) continue;
        int bsv = bs[j];
        int b = bsv >> 16, slot = bsv & 0xFFFF;
        int row = rows[idx];          // L1/L2-hot re-read
        int col = cols[idx];
        float v = vals[idx];
        int inrow = row - b * RPB;
        int pos = lbase[b] + slot;
        if (pos < (b + 1) * CAPB)
            binned[pos] = make_int2(col | (inrow << 17), __float_as_int(v));
    }
}

// inclusive scan across a 1024-thread block; wsum is 16-int shared
__device__ __forceinline__ int block_scan_1024(int v, int* wsum) {
    int tid = threadIdx.x, lane = tid & 63, wid = tid >> 6;
    int s = v;
#pragma unroll
    for (int d = 1; d < 64; d <<= 1) {
        int t = __shfl_up(s, d);
        if (lane >= d) s += t;
    }
    if (lane == 63) wsum[wid] = s;
    __syncthreads();
    if (tid < 16) {
        int ws = wsum[tid];
#pragma unroll
        for (int d = 1; d < 16; d <<= 1) {
            int t = __shfl_up(ws, d);
            if (tid >= d) ws += t;
        }
        wsum[tid] = ws;
    }
    __syncthreads();
    int wpref = (wid > 0) ? wsum[wid - 1] : 0;
    return wpref + s;
}

// block 0: user buckets, block 1: item buckets. cntb[b], ebase[b] (exclusive)
__global__ void scan_buckets(const int* __restrict__ gcurU, int BU, int* cntbU, int* ebaseU,
                             const int* __restrict__ gcurI, int BI, int* cntbI, int* ebaseI) {
    __shared__ int wsum[16];
    const int* gcur; int B; int* cntb; int* ebase;
    if (blockIdx.x == 0) { gcur = gcurU; B = BU; cntb = cntbU; ebase = ebaseU; }
    else { gcur = gcurI; B = BI; cntb = cntbI; ebase = ebaseI; }
    int t = threadIdx.x;
    int v = 0;
    if (t < B) {
        v = gcur[t * 16] - t * CAPB;
        if (v < 0) v = 0;
        if (v > CAPB) v = CAPB;
    }
    int incl = block_scan_1024(v, wsum);
    if (t < B) { cntb[t] = v; ebase[t] = incl - v; }
}

// one workgroup per bucket: stage records in LDS, count rows, scan, emit CSR
__global__ __launch_bounds__(256) void finalize_csr(
    const int2* __restrict__ binned, const int* __restrict__ cntb,
    const int* __restrict__ ebase, int RPB, int n,
    int2* __restrict__ ccv, int* __restrict__ off) {
    __shared__ int2 rec[CAPB];
    __shared__ int cnt_r[256];
    __shared__ int excl[257];
    __shared__ int curs[256];
    int b = blockIdx.x;
    int t = threadIdx.x;
    int r0 = b * RPB;
    int nrows = n - r0; if (nrows > RPB) nrows = RPB;
    if (nrows <= 0) return;
    int cnt = cntb[b];
    int eb  = ebase[b];
    const int2* src = binned + (size_t)b * CAPB;
    cnt_r[t] = 0;
    __syncthreads();
    for (int p = t; p < cnt; p += 256) {
        int2 r = src[p];
        rec[p] = r;
        atomicAdd(&cnt_r[(r.x >> 17) & 0xFF], 1);
    }
    __syncthreads();
    // exclusive scan of 256 counters: wave 0, 4 segments of 64 with carry
    if (t < 64) {
        int carry = 0;
#pragma unroll
        for (int seg = 0; seg < 4; ++seg) {
            int i = seg * 64 + t;
            int v = cnt_r[i];
            int s = v;
#pragma unroll
            for (int d = 1; d < 64; d <<= 1) {
                int u2 = __shfl_up(s, d);
                if (t >= d) s += u2;
            }
            excl[i] = carry + s - v;
            carry += __shfl(s, 63);
        }
        if (t == 0) excl[256] = carry;
    }
    __syncthreads();
    curs[t] = excl[t];
    if (t < nrows) off[r0 + t] = eb + excl[t];
    if (t == 0 && r0 + nrows == n) off[n] = eb + cnt;
    __syncthreads();
    for (int p = t; p < cnt; p += 256) {
        int2 r = rec[p];
        int inrow = (r.x >> 17) & 0xFF;
        int slot = atomicAdd(&curs[inrow], 1);
        ccv[eb + slot] = make_int2(r.x & 0x1FFFF, r.y);
    }
}

// ---------------- f32 -> bf16 cast (RNE), vectorized ----------------

__device__ __forceinline__ ushort bf16_rne(float f) {
    uint u = __float_as_uint(f);
    return (ushort)((u + 0x7fffu + ((u >> 16) & 1u)) >> 16);
}

__global__ void cast_bf16(const float4* __restrict__ au, ushort* __restrict__ ou, long n4u,
                          const float4* __restrict__ ai, ushort* __restrict__ oi, long n4i) {
    long i = (long)blockIdx.x * blockDim.x + threadIdx.x;
    long tot = n4u + n4i;
    if (i >= tot) return;
    const float4* a; ushort* o; long j;
    if (i < n4u) { a = au; o = ou; j = i; }
    else { a = ai; o = oi; j = i - n4u; }
    float4 v = a[j];
    ushort4 r;
    r.x = bf16_rne(v.x); r.y = bf16_rne(v.y); r.z = bf16_rne(v.z); r.w = bf16_rne(v.w);
    *(ushort4*)(o + j * 4) = r;
}

// ---------------- fused SPMM + MFMA dense + leaky_relu + L2 norm ----------------
// Block = 4 waves, 64-row tile; wave owns 16 rows, processed in 4 passes of 4 rows.
// Each 16-lane group owns ONE row per pass (lane q holds features 4q..4q+3) and
// pipelines its edge list 4-deep: 4 ccv records loaded, then 4 independent row
// gathers (uint2, 8B/lane) in flight -> 16 outstanding gathers per wave.
// Gathered rows go to per-wave LDS X tile [16][72] bf16 (pad 64->72).
// W staged once in LDS [64][72] bf16. Dense: X(16x64)@W^T via 8x
// mfma_f32_16x16x32_bf16 (B-frag = W[n][k] contiguous 16B LDS reads). C/D layout
// (verified): col=lane&15, row=(lane>>4)*4+reg. Norm: 4-step shfl_xor butterfly.
// x and y MUST be distinct buffers (gather reads random rows).

__global__ __launch_bounds__(256, 4) void spmm_mfma(
    const int* __restrict__ uoff, const int2* __restrict__ ccvU,
    const ushort* __restrict__ xu, const float* __restrict__ Wu, const float* __restrict__ bu,
    float* __restrict__ yfu, ushort* __restrict__ ybu, int nu, int gbu,
    const int* __restrict__ ioff, const int2* __restrict__ ccvI,
    const ushort* __restrict__ xi, const float* __restrict__ Wi, const float* __restrict__ bi,
    float* __restrict__ yfi, ushort* __restrict__ ybi, int ni) {
    __shared__ ushort wt[64 * 72];       // W row-major bf16, rows padded to 72
    __shared__ ushort xt[4 * 16 * 72];   // per-wave X tiles
    int tid = threadIdx.x;
    int lane = tid & 63, wid = tid >> 6;
    int q = lane & 15, g = lane >> 4;
    const int* off; const int2* ccv; const ushort* x; const float* W; const float* bv;
    float* yf; ushort* yb; int n; int b; int nblocks;
    if ((int)blockIdx.x < gbu) {
        off = uoff; ccv = ccvU; x = xu; W = Wu; bv = bu; yf = yfu; yb = ybu; n = nu;
        b = blockIdx.x; nblocks = gbu;
    } else {
        off = ioff; ccv = ccvI; x = xi; W = Wi; bv = bi; yf = yfi; yb = ybi; n = ni;
        b = blockIdx.x - gbu; nblocks = gridDim.x - gbu;
    }
    // stage W: coalesced read, bf16 into padded LDS
    for (int idx = tid; idx < EMB * EMB; idx += 256) {
        int r = idx >> 6, c = idx & 63;
        wt[r * 72 + c] = bf16_rne(W[idx]);
    }
    float bias[4];
#pragma unroll
    for (int t = 0; t < 4; ++t) bias[t] = bv[16 * t + q];
    __syncthreads();

    const uint2* xv2 = (const uint2*)x;
    ushort* xw = xt + wid * (16 * 72);
    int ntiles = (n + 63) >> 6;
    for (int tile = b; tile < ntiles; tile += nblocks) {
        int rowW = (tile << 6) + wid * 16;   // wave's first row
        // ---- gather 16 rows into LDS X tile: 4 passes, one row per group ----
#pragma unroll
        for (int j = 0; j < 4; ++j) {
            int rr = j * 4 + g;              // tile-local row for this group
            int row = rowW + rr;
            float av[4] = {0.f, 0.f, 0.f, 0.f};
            if (row < n) {
                int s = off[row], e = off[row + 1];
                for (int p = s; p < e; p += 4) {
                    int i1 = (p + 1 < e) ? p + 1 : e - 1;
                    int i2 = (p + 2 < e) ? p + 2 : e - 1;
                    int i3 = (p + 3 < e) ? p + 3 : e - 1;
                    int2 e0 = ccv[p], e1 = ccv[i1], e2 = ccv[i2], e3 = ccv[i3];
                    float v0 = __int_as_float(e0.y);
                    float v1 = (p + 1 < e) ? __int_as_float(e1.y) : 0.f;
                    float v2 = (p + 2 < e) ? __int_as_float(e2.y) : 0.f;
                    float v3 = (p + 3 < e) ? __int_as_float(e3.y) : 0.f;
                    uint2 g0 = xv2[(size_t)e0.x * 16 + q];
                    uint2 g1 = xv2[(size_t)e1.x * 16 + q];
                    uint2 g2 = xv2[(size_t)e2.x * 16 + q];
                    uint2 g3 = xv2[(size_t)e3.x * 16 + q];
                    av[0] = fmaf(v0, __uint_as_float(g0.x << 16), av[0]);
                    av[1] = fmaf(v0, __uint_as_float(g0.x & 0xffff0000u), av[1]);
                    av[2] = fmaf(v0, __uint_as_float(g0.y << 16), av[2]);
                    av[3] = fmaf(v0, __uint_as_float(g0.y & 0xffff0000u), av[3]);
                    av[0] = fmaf(v1, __uint_as_float(g1.x << 16), av[0]);
                    av[1] = fmaf(v1, __uint_as_float(g1.x & 0xffff0000u), av[1]);
                    av[2] = fmaf(v1, __uint_as_float(g1.y << 16), av[2]);
                    av[3] = fmaf(v1, __uint_as_float(g1.y & 0xffff0000u), av[3]);
                    av[0] = fmaf(v2, __uint_as_float(g2.x << 16), av[0]);
                    av[1] = fmaf(v2, __uint_as_float(g2.x & 0xffff0000u), av[1]);
                    av[2] = fmaf(v2, __uint_as_float(g2.y << 16), av[2]);
                    av[3] = fmaf(v2, __uint_as_float(g2.y & 0xffff0000u), av[3]);
                    av[0] = fmaf(v3, __uint_as_float(g3.x << 16), av[0]);
                    av[1] = fmaf(v3, __uint_as_float(g3.x & 0xffff0000u), av[1]);
                    av[2] = fmaf(v3, __uint_as_float(g3.y << 16), av[2]);
                    av[3] = fmaf(v3, __uint_as_float(g3.y & 0xffff0000u), av[3]);
                }
            }
            // all 64 lanes write: group g writes its row rr (16 lanes x 8B)
            uint p0 = (uint)bf16_rne(av[0]) | ((uint)bf16_rne(av[1]) << 16);
            uint p1 = (uint)bf16_rne(av[2]) | ((uint)bf16_rne(av[3]) << 16);
            *(uint2*)(xw + rr * 72 + q * 4) = make_uint2(p0, p1);
        }
        __syncthreads();   // X tiles visible (cross-lane/cross-wave)

        // ---- dense: D(16x64) = X @ W^T, 2 K-steps x 4 N-tiles ----
        f32x4 ac0 = {0.f, 0.f, 0.f, 0.f}, ac1 = ac0, ac2 = ac0, ac3 = ac0;
#pragma unroll
        for (int ks = 0; ks < 2; ++ks) {
            bf16x8 af = *(const bf16x8*)(xw + q * 72 + g * 8 + ks * 32);
            bf16x8 b0 = *(const bf16x8*)(wt + (q +  0) * 72 + g * 8 + ks * 32);
            bf16x8 b1 = *(const bf16x8*)(wt + (q + 16) * 72 + g * 8 + ks * 32);
            bf16x8 b2 = *(const bf16x8*)(wt + (q + 32) * 72 + g * 8 + ks * 32);
            bf16x8 b3 = *(const bf16x8*)(wt + (q + 48) * 72 + g * 8 + ks * 32);
            ac0 = __builtin_amdgcn_mfma_f32_16x16x32_bf16(af, b0, ac0, 0, 0, 0);
            ac1 = __builtin_amdgcn_mfma_f32_16x16x32_bf16(af, b1, ac1, 0, 0, 0);
            ac2 = __builtin_amdgcn_mfma_f32_16x16x32_bf16(af, b2, ac2, 0, 0, 0);
            ac3 = __builtin_amdgcn_mfma_f32_16x16x32_bf16(af, b3, ac3, 0, 0, 0);
        }
        __syncthreads();   // safe to overwrite X next iteration

        // ---- bias + leaky_relu + L2 norm + store ----
        // lane holds D[row=g*4+r][col=q+16t] for t,r in 0..3
        float dv[4][4];
        float ss[4] = {0.f, 0.f, 0.f, 0.f};
#pragma unroll
        for (int t = 0; t < 4; ++t) {
            f32x4 a = (t == 0) ? ac0 : (t == 1) ? ac1 : (t == 2) ? ac2 : ac3;
#pragma unroll
            for (int r = 0; r < 4; ++r) {
                float d = a[r] + bias[t];
                d = (d > 0.f) ? d : 0.01f * d;
                dv[t][r] = d;
                ss[r] = fmaf(d, d, ss[r]);
            }
        }
#pragma unroll
        for (int r = 0; r < 4; ++r) {
            float s2 = ss[r];
            s2 += __shfl_xor(s2, 1);
            s2 += __shfl_xor(s2, 2);
            s2 += __shfl_xor(s2, 4);
            s2 += __shfl_xor(s2, 8);
            float scl = 1.0f / fmaxf(sqrtf(s2), 1e-12f);
            int orow = rowW + g * 4 + r;
            if (orow < n) {
#pragma unroll
                for (int t = 0; t < 4; ++t) {
                    float outv = dv[t][r] * scl;
                    size_t cidx = (size_t)orow * EMB + 16 * t + q;
                    if (yb) yb[cidx] = bf16_rne(outv);
                    else    yf[cidx] = outv;
                }
            }
        }
    }
}

// ---------------- launch ----------------

extern "C" void kernel_launch(void* const* d_in, const int* in_sizes, int n_in,
                              void* d_out, int out_size, void* d_ws, size_t ws_size,
                              hipStream_t stream) {
    const float* user_emb = (const float*)d_in[0];
    const float* item_emb = (const float*)d_in[1];
    const float* Wu0 = (const float*)d_in[2];
    const float* bu0 = (const float*)d_in[3];
    const float* Wu1 = (const float*)d_in[4];
    const float* bu1 = (const float*)d_in[5];
    const float* Wi0 = (const float*)d_in[6];
    const float* bi0 = (const float*)d_in[7];
    const float* Wi1 = (const float*)d_in[8];
    const float* bi1 = (const float*)d_in[9];
    const int*   u_rows = (const int*)d_in[10];
    const int*   u_cols = (const int*)d_in[11];
    const float* u_vals = (const float*)d_in[12];
    const int*   i_rows = (const int*)d_in[13];
    const int*   i_cols = (const int*)d_in[14];
    const float* i_vals = (const float*)d_in[15];

    const int nu = in_sizes[0] / EMB;
    const int ni = in_sizes[1] / EMB;
    const int eu = in_sizes[10];
    const int ei = in_sizes[13];

    const int BU = 512, BI = 256;
    const int RPBU = (nu + BU - 1) / BU;   // 196
    const int RPBI = (ni + BI - 1) / BI;   // 196

    float* out_u = (float*)d_out;
    float* out_i = out_u + (size_t)nu * EMB;

    // workspace carve (256B aligned)
    size_t o = 0;
    char* wsb = (char*)d_ws;
    auto carve = [&](size_t bytes) -> void* {
        void* p = wsb + o;
        o += (bytes + 255) & ~(size_t)255;
        return p;
    };
    ushort* xbu0 = (ushort*)carve((size_t)nu * EMB * 2);   // bf16 cast of user_emb
    ushort* xbi0 = (ushort*)carve((size_t)ni * EMB * 2);   // bf16 cast of item_emb
    // region shared in time: binned records (CSR build) -> layer-0 bf16 outputs
    size_t binnedU_bytes = (size_t)BU * CAPB * 8;
    size_t binnedI_bytes = (size_t)BI * CAPB * 8;
    size_t xb1_bytes = ((size_t)nu + ni) * EMB * 2;
    size_t shared_bytes = binnedU_bytes + binnedI_bytes;
    if (xb1_bytes > shared_bytes) shared_bytes = xb1_bytes;
    char* regionA = (char*)carve(shared_bytes);
    int2* binnedU = (int2*)regionA;
    int2* binnedI = (int2*)(regionA + binnedU_bytes);
    ushort* xbu1 = (ushort*)regionA;                        // aliases binned (dead by then)
    ushort* xbi1 = (ushort*)(regionA + (size_t)nu * EMB * 2);
    int2* ccvU  = (int2*)carve((size_t)eu * 8);
    int2* ccvI  = (int2*)carve((size_t)ei * 8);
    int*  uoff  = (int*)carve((size_t)(nu + 1) * 4);
    int*  ioff  = (int*)carve((size_t)(ni + 1) * 4);
    int*  gcurU = (int*)carve((size_t)BU * 16 * 4);
    int*  gcurI = (int*)carve((size_t)BI * 16 * 4);
    int*  cntbU = (int*)carve((size_t)BU * 4);
    int*  ebaseU= (int*)carve((size_t)BU * 4);
    int*  cntbI = (int*)carve((size_t)BI * 4);
    int*  ebaseI= (int*)carve((size_t)BI * 4);
    (void)ws_size;

    // ---- CSR build via bucket sort ----
    init_cursors<<<(BU + BI + 255) / 256, 256, 0, stream>>>(gcurU, gcurI, BU, BI);
    bin_edges<<<(eu + CHUNK - 1) / CHUNK, 256, 0, stream>>>(
        u_rows, u_cols, u_vals, eu, BU, RPBU, gcurU, binnedU);
    bin_edges<<<(ei + CHUNK - 1) / CHUNK, 256, 0, stream>>>(
        i_rows, i_cols, i_vals, ei, BI, RPBI, gcurI, binnedI);
    scan_buckets<<<2, 1024, 0, stream>>>(gcurU, BU, cntbU, ebaseU,
                                         gcurI, BI, cntbI, ebaseI);
    finalize_csr<<<BU, 256, 0, stream>>>(binnedU, cntbU, ebaseU, RPBU, nu, ccvU, uoff);
    finalize_csr<<<BI, 256, 0, stream>>>(binnedI, cntbI, ebaseI, RPBI, ni, ccvI, ioff);

    // ---- cast input embeddings to bf16 ----
    {
        long n4u = (long)nu * EMB / 4, n4i = (long)ni * EMB / 4;
        long tot = n4u + n4i;
        cast_bf16<<<(int)((tot + 255) / 256), 256, 0, stream>>>(
            (const float4*)user_emb, xbu0, n4u, (const float4*)item_emb, xbi0, n4i);
    }

    // ---- 2 GCN layers, fused per layer; ping-pong bf16 buffers ----
    const int GBU = 683, GBI = 341;   // 1024 blocks = 4 blocks/CU (round-6 regime)
    // layer 0: bf16(emb) -> bf16 tmp (tmp aliases binned, which is dead now)
    spmm_mfma<<<GBU + GBI, 256, 0, stream>>>(
        uoff, ccvU, xbu0, Wu0, bu0, nullptr, xbu1, nu, GBU,
        ioff, ccvI, xbi0, Wi0, bi0, nullptr, xbi1, ni);
    // layer 1: bf16 tmp -> f32 out
    spmm_mfma<<<GBU + GBI, 256, 0, stream>>>(
        uoff, ccvU, xbu1, Wu1, bu1, out_u, nullptr, nu, GBU,
        ioff, ccvI, xbi1, Wi1, bi1, out_i, nullptr, ni);
}

// Round 11
// 205.817 us; speedup vs baseline: 5.5126x; 1.1757x over previous
//
#include <hip/hip_runtime.h>
#include <hip/hip_bf16.h>
#include <math.h>

#define EMB 64
#define CAPB 3584      // per-bucket slot capacity (mean 3125, sigma ~56 -> 8.2 sigma)
#define CHUNK 4096     // edges per bin block

typedef __attribute__((ext_vector_type(8))) short bf16x8;
typedef __attribute__((ext_vector_type(4))) float f32x4;

__device__ __forceinline__ ushort bf16_rne(float f) {
    uint u = __float_as_uint(f);
    return (ushort)((u + 0x7fffu + ((u >> 16) & 1u)) >> 16);
}

// ---------------- prep kernel: bin_edges(U) | bin_edges(I) | cast_bf16 ----------------
// gcur assumed zeroed (hipMemsetAsync). Record: int2(col | inrow<<17, f32val).

__device__ __forceinline__ void bin_body(
    const int* __restrict__ rows, const int* __restrict__ cols,
    const float* __restrict__ vals, int nE, int B, int RPB,
    int* gcur, int2* __restrict__ binned, int blk,
    int* cnt, int* lbase) {
    int t = threadIdx.x;
    for (int i = t; i < B; i += 256) cnt[i] = 0;
    __syncthreads();
    int c0 = blk * CHUNK;
    int bs[16];
#pragma unroll
    for (int j = 0; j < 16; ++j) {
        int idx = c0 + t + j * 256;
        int bsv = -1;
        if (idx < nE) {
            int row = rows[idx];
            int b = row / RPB;
            int slot = atomicAdd(&cnt[b], 1);
            bsv = (b << 16) | slot;
        }
        bs[j] = bsv;
    }
    __syncthreads();
    for (int i = t; i < B; i += 256) {
        int c = cnt[i];
        lbase[i] = c ? atomicAdd(&gcur[i * 16], c) : 0;
    }
    __syncthreads();
#pragma unroll
    for (int j = 0; j < 16; ++j) {
        int idx = c0 + t + j * 256;
        if (idx >= nE) continue;
        int bsv = bs[j];
        int b = bsv >> 16, slot = bsv & 0xFFFF;
        int row = rows[idx];          // L1/L2-hot re-read
        int col = cols[idx];
        float v = vals[idx];
        int inrow = row - b * RPB;
        int pos = lbase[b] + slot;
        if (pos < CAPB)
            binned[(size_t)b * CAPB + pos] = make_int2(col | (inrow << 17), __float_as_int(v));
    }
}

__global__ __launch_bounds__(256) void prep(
    const int* __restrict__ u_rows, const int* __restrict__ u_cols,
    const float* __restrict__ u_vals, int eu, int BU, int RPBU,
    int* gcurU, int2* __restrict__ binnedU, int nbU,
    const int* __restrict__ i_rows, const int* __restrict__ i_cols,
    const float* __restrict__ i_vals, int ei, int BI, int RPBI,
    int* gcurI, int2* __restrict__ binnedI, int nbI,
    const float4* __restrict__ embU, ushort* __restrict__ xbU, long n4u,
    const float4* __restrict__ embI, ushort* __restrict__ xbI, long n4i,
    int nbCast) {
    __shared__ int cnt[512];
    __shared__ int lbase[512];
    int b = blockIdx.x;
    if (b < nbU) { bin_body(u_rows, u_cols, u_vals, eu, BU, RPBU, gcurU, binnedU, b, cnt, lbase); return; }
    b -= nbU;
    if (b < nbI) { bin_body(i_rows, i_cols, i_vals, ei, BI, RPBI, gcurI, binnedI, b, cnt, lbase); return; }
    b -= nbI;
    // cast: 4 float4 per thread, strided
    long tot = n4u + n4i;
    long base = (long)b * 1024 + threadIdx.x;
#pragma unroll
    for (int k = 0; k < 4; ++k) {
        long i = base + k * 256;
        if (i >= tot) return;
        const float4* a; ushort* o; long j;
        if (i < n4u) { a = embU; o = xbU; j = i; }
        else { a = embI; o = xbI; j = i - n4u; }
        float4 v = a[j];
        ushort4 r;
        r.x = bf16_rne(v.x); r.y = bf16_rne(v.y); r.z = bf16_rne(v.z); r.w = bf16_rne(v.w);
        *(ushort4*)(o + j * 4) = r;
    }
}

// inclusive scan across a 1024-thread block; wsum is 16-int shared
__device__ __forceinline__ int block_scan_1024(int v, int* wsum) {
    int tid = threadIdx.x, lane = tid & 63, wid = tid >> 6;
    int s = v;
#pragma unroll
    for (int d = 1; d < 64; d <<= 1) {
        int t = __shfl_up(s, d);
        if (lane >= d) s += t;
    }
    if (lane == 63) wsum[wid] = s;
    __syncthreads();
    if (tid < 16) {
        int ws = wsum[tid];
#pragma unroll
        for (int d = 1; d < 16; d <<= 1) {
            int t = __shfl_up(ws, d);
            if (tid >= d) ws += t;
        }
        wsum[tid] = ws;
    }
    __syncthreads();
    int wpref = (wid > 0) ? wsum[wid - 1] : 0;
    return wpref + s;
}

// block 0: user buckets, block 1: item buckets. cntb[b], ebase[b] (exclusive)
__global__ void scan_buckets(const int* __restrict__ gcurU, int BU, int* cntbU, int* ebaseU,
                             const int* __restrict__ gcurI, int BI, int* cntbI, int* ebaseI) {
    __shared__ int wsum[16];
    const int* gcur; int B; int* cntb; int* ebase;
    if (blockIdx.x == 0) { gcur = gcurU; B = BU; cntb = cntbU; ebase = ebaseU; }
    else { gcur = gcurI; B = BI; cntb = cntbI; ebase = ebaseI; }
    int t = threadIdx.x;
    int v = 0;
    if (t < B) {
        v = gcur[t * 16];
        if (v < 0) v = 0;
        if (v > CAPB) v = CAPB;
    }
    int incl = block_scan_1024(v, wsum);
    if (t < B) { cntb[t] = v; ebase[t] = incl - v; }
}

// one workgroup per bucket (U buckets then I buckets): stage records in LDS,
// count rows, scan, emit CSR
__global__ __launch_bounds__(256) void finalize_csr(
    const int2* __restrict__ binnedU, const int* __restrict__ cntbU,
    const int* __restrict__ ebaseU, int RPBU, int nu,
    int2* __restrict__ ccvU, int* __restrict__ uoff, int BU,
    const int2* __restrict__ binnedI, const int* __restrict__ cntbI,
    const int* __restrict__ ebaseI, int RPBI, int ni,
    int2* __restrict__ ccvI, int* __restrict__ ioff) {
    __shared__ int2 rec[CAPB];
    __shared__ int cnt_r[256];
    __shared__ int excl[257];
    __shared__ int curs[256];
    int b = blockIdx.x;
    const int2* binned; const int* cntb; const int* ebase; int RPB; int n;
    int2* ccv; int* off;
    if (b < BU) {
        binned = binnedU; cntb = cntbU; ebase = ebaseU; RPB = RPBU; n = nu;
        ccv = ccvU; off = uoff;
    } else {
        b -= BU;
        binned = binnedI; cntb = cntbI; ebase = ebaseI; RPB = RPBI; n = ni;
        ccv = ccvI; off = ioff;
    }
    int t = threadIdx.x;
    int r0 = b * RPB;
    int nrows = n - r0; if (nrows > RPB) nrows = RPB;
    if (nrows <= 0) return;
    int cnt = cntb[b];
    int eb  = ebase[b];
    const int2* src = binned + (size_t)b * CAPB;
    cnt_r[t] = 0;
    __syncthreads();
    for (int p = t; p < cnt; p += 256) {
        int2 r = src[p];
        rec[p] = r;
        atomicAdd(&cnt_r[(r.x >> 17) & 0xFF], 1);
    }
    __syncthreads();
    // exclusive scan of 256 counters: wave 0, 4 segments of 64 with carry
    if (t < 64) {
        int carry = 0;
#pragma unroll
        for (int seg = 0; seg < 4; ++seg) {
            int i = seg * 64 + t;
            int v = cnt_r[i];
            int s = v;
#pragma unroll
            for (int d = 1; d < 64; d <<= 1) {
                int u2 = __shfl_up(s, d);
                if (t >= d) s += u2;
            }
            excl[i] = carry + s - v;
            carry += __shfl(s, 63);
        }
        if (t == 0) excl[256] = carry;
    }
    __syncthreads();
    curs[t] = excl[t];
    if (t < nrows) off[r0 + t] = eb + excl[t];
    if (t == 0 && r0 + nrows == n) off[n] = eb + cnt;
    __syncthreads();
    for (int p = t; p < cnt; p += 256) {
        int2 r = rec[p];
        int inrow = (r.x >> 17) & 0xFF;
        int slot = atomicAdd(&curs[inrow], 1);
        ccv[eb + slot] = make_int2(r.x & 0x1FFFF, r.y);
    }
}

// ---------------- fused SPMM + MFMA dense + leaky_relu + L2 norm ----------------
// ONE 64-row tile per block (grid = ntU + ntI): HW dispatcher load-balances.
// Block = 4 waves; wave owns 16 rows in 4 passes of 4 rows; each 16-lane group
// owns ONE row per pass (lane q holds features 4q..4q+3) with an 8-deep edge
// pipeline: 8 records then 8 independent row gathers (uint2, 8B/lane) in flight
// -> 32 outstanding gathers per wave. Rows land in per-wave LDS X tile [16][72]
// bf16. W staged per block in LDS [64][72] bf16. Dense: X(16x64)@W^T via 8x
// mfma_f32_16x16x32_bf16. C/D layout (verified): col=lane&15, row=(lane>>4)*4+reg.
// Norm: 4-step shfl_xor butterfly. x and y MUST be distinct buffers.

__global__ __launch_bounds__(256, 4) void spmm_mfma(
    const int* __restrict__ uoff, const int2* __restrict__ ccvU,
    const ushort* __restrict__ xu, const float* __restrict__ Wu, const float* __restrict__ bu,
    float* __restrict__ yfu, ushort* __restrict__ ybu, int nu, int ntU,
    const int* __restrict__ ioff, const int2* __restrict__ ccvI,
    const ushort* __restrict__ xi, const float* __restrict__ Wi, const float* __restrict__ bi,
    float* __restrict__ yfi, ushort* __restrict__ ybi, int ni) {
    __shared__ ushort wt[64 * 72];       // W row-major bf16, rows padded to 72
    __shared__ ushort xt[4 * 16 * 72];   // per-wave X tiles
    int tid = threadIdx.x;
    int lane = tid & 63, wid = tid >> 6;
    int q = lane & 15, g = lane >> 4;
    int tile = blockIdx.x;
    const int* off; const int2* ccv; const ushort* x; const float* W; const float* bv;
    float* yf; ushort* yb; int n;
    if (tile < ntU) {
        off = uoff; ccv = ccvU; x = xu; W = Wu; bv = bu; yf = yfu; yb = ybu; n = nu;
    } else {
        tile -= ntU;
        off = ioff; ccv = ccvI; x = xi; W = Wi; bv = bi; yf = yfi; yb = ybi; n = ni;
    }
    // stage W: coalesced read, bf16 into padded LDS
    for (int idx = tid; idx < EMB * EMB; idx += 256) {
        int r = idx >> 6, c = idx & 63;
        wt[r * 72 + c] = bf16_rne(W[idx]);
    }
    float bias[4];
#pragma unroll
    for (int t = 0; t < 4; ++t) bias[t] = bv[16 * t + q];
    __syncthreads();

    const uint2* xv2 = (const uint2*)x;
    ushort* xw = xt + wid * (16 * 72);
    int rowW = (tile << 6) + wid * 16;   // wave's first row

    // ---- gather 16 rows into LDS X tile: 4 passes, one row per group ----
#pragma unroll
    for (int j = 0; j < 4; ++j) {
        int rr = j * 4 + g;              // tile-local row for this group
        int row = rowW + rr;
        float av[4] = {0.f, 0.f, 0.f, 0.f};
        if (row < n) {
            int s = off[row], e = off[row + 1];
            for (int p = s; p < e; p += 8) {
                int2 ed[8];
                uint2 gx[8];
#pragma unroll
                for (int k = 0; k < 8; ++k) {
                    int idx = p + k;
                    idx = (idx < e) ? idx : (e - 1);
                    ed[k] = ccv[idx];
                }
#pragma unroll
                for (int k = 0; k < 8; ++k)
                    gx[k] = xv2[(size_t)(uint)ed[k].x * 16 + q];
#pragma unroll
                for (int k = 0; k < 8; ++k) {
                    float v = (p + k < e) ? __int_as_float(ed[k].y) : 0.f;
                    av[0] = fmaf(v, __uint_as_float(gx[k].x << 16), av[0]);
                    av[1] = fmaf(v, __uint_as_float(gx[k].x & 0xffff0000u), av[1]);
                    av[2] = fmaf(v, __uint_as_float(gx[k].y << 16), av[2]);
                    av[3] = fmaf(v, __uint_as_float(gx[k].y & 0xffff0000u), av[3]);
                }
            }
        }
        // group g writes its row rr (16 lanes x 8B, conflict-free)
        uint p0 = (uint)bf16_rne(av[0]) | ((uint)bf16_rne(av[1]) << 16);
        uint p1 = (uint)bf16_rne(av[2]) | ((uint)bf16_rne(av[3]) << 16);
        *(uint2*)(xw + rr * 72 + q * 4) = make_uint2(p0, p1);
    }
    __syncthreads();   // X tiles visible (cross-lane/cross-wave)

    // ---- dense: D(16x64) = X @ W^T, 2 K-steps x 4 N-tiles ----
    f32x4 ac0 = {0.f, 0.f, 0.f, 0.f}, ac1 = ac0, ac2 = ac0, ac3 = ac0;
#pragma unroll
    for (int ks = 0; ks < 2; ++ks) {
        bf16x8 af = *(const bf16x8*)(xw + q * 72 + g * 8 + ks * 32);
        bf16x8 b0 = *(const bf16x8*)(wt + (q +  0) * 72 + g * 8 + ks * 32);
        bf16x8 b1 = *(const bf16x8*)(wt + (q + 16) * 72 + g * 8 + ks * 32);
        bf16x8 b2 = *(const bf16x8*)(wt + (q + 32) * 72 + g * 8 + ks * 32);
        bf16x8 b3 = *(const bf16x8*)(wt + (q + 48) * 72 + g * 8 + ks * 32);
        ac0 = __builtin_amdgcn_mfma_f32_16x16x32_bf16(af, b0, ac0, 0, 0, 0);
        ac1 = __builtin_amdgcn_mfma_f32_16x16x32_bf16(af, b1, ac1, 0, 0, 0);
        ac2 = __builtin_amdgcn_mfma_f32_16x16x32_bf16(af, b2, ac2, 0, 0, 0);
        ac3 = __builtin_amdgcn_mfma_f32_16x16x32_bf16(af, b3, ac3, 0, 0, 0);
    }

    // ---- bias + leaky_relu + L2 norm + store ----
    // lane holds D[row=g*4+r][col=q+16t] for t,r in 0..3
    float dv[4][4];
    float ss[4] = {0.f, 0.f, 0.f, 0.f};
#pragma unroll
    for (int t = 0; t < 4; ++t) {
        f32x4 a = (t == 0) ? ac0 : (t == 1) ? ac1 : (t == 2) ? ac2 : ac3;
#pragma unroll
        for (int r = 0; r < 4; ++r) {
            float d = a[r] + bias[t];
            d = (d > 0.f) ? d : 0.01f * d;
            dv[t][r] = d;
            ss[r] = fmaf(d, d, ss[r]);
        }
    }
#pragma unroll
    for (int r = 0; r < 4; ++r) {
        float s2 = ss[r];
        s2 += __shfl_xor(s2, 1);
        s2 += __shfl_xor(s2, 2);
        s2 += __shfl_xor(s2, 4);
        s2 += __shfl_xor(s2, 8);
        float scl = 1.0f / fmaxf(sqrtf(s2), 1e-12f);
        int orow = rowW + g * 4 + r;
        if (orow < n) {
#pragma unroll
            for (int t = 0; t < 4; ++t) {
                float outv = dv[t][r] * scl;
                size_t cidx = (size_t)orow * EMB + 16 * t + q;
                if (yb) yb[cidx] = bf16_rne(outv);
                else    yf[cidx] = outv;
            }
        }
    }
}

// ---------------- launch ----------------

extern "C" void kernel_launch(void* const* d_in, const int* in_sizes, int n_in,
                              void* d_out, int out_size, void* d_ws, size_t ws_size,
                              hipStream_t stream) {
    const float* user_emb = (const float*)d_in[0];
    const float* item_emb = (const float*)d_in[1];
    const float* Wu0 = (const float*)d_in[2];
    const float* bu0 = (const float*)d_in[3];
    const float* Wu1 = (const float*)d_in[4];
    const float* bu1 = (const float*)d_in[5];
    const float* Wi0 = (const float*)d_in[6];
    const float* bi0 = (const float*)d_in[7];
    const float* Wi1 = (const float*)d_in[8];
    const float* bi1 = (const float*)d_in[9];
    const int*   u_rows = (const int*)d_in[10];
    const int*   u_cols = (const int*)d_in[11];
    const float* u_vals = (const float*)d_in[12];
    const int*   i_rows = (const int*)d_in[13];
    const int*   i_cols = (const int*)d_in[14];
    const float* i_vals = (const float*)d_in[15];

    const int nu = in_sizes[0] / EMB;
    const int ni = in_sizes[1] / EMB;
    const int eu = in_sizes[10];
    const int ei = in_sizes[13];

    const int BU = 512, BI = 256;
    const int RPBU = (nu + BU - 1) / BU;   // 196
    const int RPBI = (ni + BI - 1) / BI;   // 196

    float* out_u = (float*)d_out;
    float* out_i = out_u + (size_t)nu * EMB;

    // workspace carve (256B aligned)
    size_t o = 0;
    char* wsb = (char*)d_ws;
    auto carve = [&](size_t bytes) -> void* {
        void* p = wsb + o;
        o += (bytes + 255) & ~(size_t)255;
        return p;
    };
    ushort* xbu0 = (ushort*)carve((size_t)nu * EMB * 2);   // bf16 cast of user_emb
    ushort* xbi0 = (ushort*)carve((size_t)ni * EMB * 2);   // bf16 cast of item_emb
    // region shared in time: binned records (CSR build) -> layer-0 bf16 outputs
    size_t binnedU_bytes = (size_t)BU * CAPB * 8;
    size_t binnedI_bytes = (size_t)BI * CAPB * 8;
    size_t xb1_bytes = ((size_t)nu + ni) * EMB * 2;
    size_t shared_bytes = binnedU_bytes + binnedI_bytes;
    if (xb1_bytes > shared_bytes) shared_bytes = xb1_bytes;
    char* regionA = (char*)carve(shared_bytes);
    int2* binnedU = (int2*)regionA;
    int2* binnedI = (int2*)(regionA + binnedU_bytes);
    ushort* xbu1 = (ushort*)regionA;                        // aliases binned (dead by then)
    ushort* xbi1 = (ushort*)(regionA + (size_t)nu * EMB * 2);
    int2* ccvU  = (int2*)carve((size_t)eu * 8);
    int2* ccvI  = (int2*)carve((size_t)ei * 8);
    int*  uoff  = (int*)carve((size_t)(nu + 1) * 4);
    int*  ioff  = (int*)carve((size_t)(ni + 1) * 4);
    int*  gcur  = (int*)carve((size_t)(BU + BI) * 16 * 4); // one memset covers both
    int*  gcurU = gcur;
    int*  gcurI = gcur + (size_t)BU * 16;
    int*  cntbU = (int*)carve((size_t)BU * 4);
    int*  ebaseU= (int*)carve((size_t)BU * 4);
    int*  cntbI = (int*)carve((size_t)BI * 4);
    int*  ebaseI= (int*)carve((size_t)BI * 4);
    (void)ws_size;

    // ---- CSR build via bucket sort + embedding cast, compacted launches ----
    hipMemsetAsync(gcur, 0, (size_t)(BU + BI) * 16 * 4, stream);
    {
        int nbU = (eu + CHUNK - 1) / CHUNK;
        int nbI = (ei + CHUNK - 1) / CHUNK;
        long n4u = (long)nu * EMB / 4, n4i = (long)ni * EMB / 4;
        int nbCast = (int)((n4u + n4i + 1023) / 1024);
        prep<<<nbU + nbI + nbCast, 256, 0, stream>>>(
            u_rows, u_cols, u_vals, eu, BU, RPBU, gcurU, binnedU, nbU,
            i_rows, i_cols, i_vals, ei, BI, RPBI, gcurI, binnedI, nbI,
            (const float4*)user_emb, xbu0, n4u,
            (const float4*)item_emb, xbi0, n4i, nbCast);
    }
    scan_buckets<<<2, 1024, 0, stream>>>(gcurU, BU, cntbU, ebaseU,
                                         gcurI, BI, cntbI, ebaseI);
    finalize_csr<<<BU + BI, 256, 0, stream>>>(
        binnedU, cntbU, ebaseU, RPBU, nu, ccvU, uoff, BU,
        binnedI, cntbI, ebaseI, RPBI, ni, ccvI, ioff);

    // ---- 2 GCN layers, fused per layer; ping-pong bf16 buffers ----
    int ntU = (nu + 63) >> 6, ntI = (ni + 63) >> 6;
    // layer 0: bf16(emb) -> bf16 tmp (tmp aliases binned, which is dead now)
    spmm_mfma<<<ntU + ntI, 256, 0, stream>>>(
        uoff, ccvU, xbu0, Wu0, bu0, nullptr, xbu1, nu, ntU,
        ioff, ccvI, xbi0, Wi0, bi0, nullptr, xbi1, ni);
    // layer 1: bf16 tmp -> f32 out
    spmm_mfma<<<ntU + ntI, 256, 0, stream>>>(
        uoff, ccvU, xbu1, Wu1, bu1, out_u, nullptr, nu, ntU,
        ioff, ccvI, xbi1, Wi1, bi1, out_i, nullptr, ni);
}

// Round 12
// 195.248 us; speedup vs baseline: 5.8110x; 1.0541x over previous
//
#include <hip/hip_runtime.h>
#include <hip/hip_bf16.h>
#include <math.h>

#define EMB 64
#define CAPB 3584      // per-bucket slot capacity (mean 3125, sigma ~56 -> 8.2 sigma)
#define CHUNK 4096     // edges per bin block

typedef __attribute__((ext_vector_type(8))) short bf16x8;
typedef __attribute__((ext_vector_type(4))) float f32x4;

__device__ __forceinline__ ushort bf16_rne(float f) {
    uint u = __float_as_uint(f);
    return (ushort)((u + 0x7fffu + ((u >> 16) & 1u)) >> 16);
}

// ---------------- prep kernel: bin_edges(U) | bin_edges(I) | cast_bf16 ----------------
// gcur assumed zeroed (hipMemsetAsync). Record: int2(col | inrow<<17, f32val).
// Binned writes are LDS-staged in bucket-sorted order -> coalesced full-line runs.

__device__ __forceinline__ void bin_body(
    const int* __restrict__ rows, const int* __restrict__ cols,
    const float* __restrict__ vals, int nE, int B, int RPB,
    int* gcur, int2* __restrict__ binned, int blk,
    int* cnt, int* sstart, int* lbase, int2* rec, ushort* bkt) {
    int t = threadIdx.x;
    for (int i = t; i < B; i += 256) cnt[i] = 0;
    __syncthreads();
    int c0 = blk * CHUNK;
    int ntot = nE - c0; if (ntot > CHUNK) ntot = CHUNK;
    int bs[16];
#pragma unroll
    for (int j = 0; j < 16; ++j) {
        int idx = c0 + t + j * 256;
        int bsv = -1;
        if (idx < nE) {
            int row = rows[idx];
            int b = row / RPB;
            int inrow = row - b * RPB;
            int slot = atomicAdd(&cnt[b], 1);
            bsv = (b << 21) | (inrow << 13) | slot;   // b<512, inrow<256, slot<8192
        }
        bs[j] = bsv;
    }
    __syncthreads();
    // reserve global runs per bucket
    for (int i = t; i < B; i += 256) {
        int c = cnt[i];
        lbase[i] = c ? atomicAdd(&gcur[i * 16], c) : 0;
    }
    // exclusive scan of cnt -> sstart (wave 0, B/64 segments with carry)
    if (t < 64) {
        int carry = 0;
        int nseg = B >> 6;
        for (int seg = 0; seg < nseg; ++seg) {
            int i = seg * 64 + t;
            int v = cnt[i];
            int s = v;
#pragma unroll
            for (int d = 1; d < 64; d <<= 1) {
                int u2 = __shfl_up(s, d);
                if (t >= d) s += u2;
            }
            sstart[i] = carry + s - v;
            carry += __shfl(s, 63);
        }
    }
    __syncthreads();
    // stage records into LDS in bucket-sorted order
#pragma unroll
    for (int j = 0; j < 16; ++j) {
        int idx = c0 + t + j * 256;
        if (idx >= nE) continue;
        int bsv = bs[j];
        int b = bsv >> 21, inrow = (bsv >> 13) & 0xFF, slot = bsv & 0x1FFF;
        int col = cols[idx];
        float v = vals[idx];
        int li = sstart[b] + slot;
        rec[li] = make_int2(col | (inrow << 17), __float_as_int(v));
        bkt[li] = (ushort)b;
    }
    __syncthreads();
    // coalesced copy: consecutive i in a bucket -> consecutive global dest
    for (int i = t; i < ntot; i += 256) {
        int b = bkt[i];
        int pos = lbase[b] + (i - sstart[b]);
        if (pos < CAPB)
            binned[(size_t)b * CAPB + pos] = rec[i];
    }
}

__global__ __launch_bounds__(256) void prep(
    const int* __restrict__ u_rows, const int* __restrict__ u_cols,
    const float* __restrict__ u_vals, int eu, int BU, int RPBU,
    int* gcurU, int2* __restrict__ binnedU, int nbU,
    const int* __restrict__ i_rows, const int* __restrict__ i_cols,
    const float* __restrict__ i_vals, int ei, int BI, int RPBI,
    int* gcurI, int2* __restrict__ binnedI, int nbI,
    const float4* __restrict__ embU, ushort* __restrict__ xbU, long n4u,
    const float4* __restrict__ embI, ushort* __restrict__ xbI, long n4i,
    int nbCast) {
    __shared__ int2 rec[CHUNK];        // 32 KB
    __shared__ ushort bkt[CHUNK];      // 8 KB
    __shared__ int cnt[512];
    __shared__ int sstart[512];
    __shared__ int lbase[512];
    int b = blockIdx.x;
    if (b < nbU) {
        bin_body(u_rows, u_cols, u_vals, eu, BU, RPBU, gcurU, binnedU, b,
                 cnt, sstart, lbase, rec, bkt);
        return;
    }
    b -= nbU;
    if (b < nbI) {
        bin_body(i_rows, i_cols, i_vals, ei, BI, RPBI, gcurI, binnedI, b,
                 cnt, sstart, lbase, rec, bkt);
        return;
    }
    b -= nbI;
    // cast: 4 float4 per thread, strided
    long tot = n4u + n4i;
    long base = (long)b * 1024 + threadIdx.x;
#pragma unroll
    for (int k = 0; k < 4; ++k) {
        long i = base + k * 256;
        if (i >= tot) return;
        const float4* a; ushort* o; long j;
        if (i < n4u) { a = embU; o = xbU; j = i; }
        else { a = embI; o = xbI; j = i - n4u; }
        float4 v = a[j];
        ushort4 r;
        r.x = bf16_rne(v.x); r.y = bf16_rne(v.y); r.z = bf16_rne(v.z); r.w = bf16_rne(v.w);
        *(ushort4*)(o + j * 4) = r;
    }
}

// inclusive scan across a 1024-thread block; wsum is 16-int shared
__device__ __forceinline__ int block_scan_1024(int v, int* wsum) {
    int tid = threadIdx.x, lane = tid & 63, wid = tid >> 6;
    int s = v;
#pragma unroll
    for (int d = 1; d < 64; d <<= 1) {
        int t = __shfl_up(s, d);
        if (lane >= d) s += t;
    }
    if (lane == 63) wsum[wid] = s;
    __syncthreads();
    if (tid < 16) {
        int ws = wsum[tid];
#pragma unroll
        for (int d = 1; d < 16; d <<= 1) {
            int t = __shfl_up(ws, d);
            if (tid >= d) ws += t;
        }
        wsum[tid] = ws;
    }
    __syncthreads();
    int wpref = (wid > 0) ? wsum[wid - 1] : 0;
    return wpref + s;
}

// block 0: user buckets, block 1: item buckets. cntb[b], ebase[b] (exclusive)
__global__ void scan_buckets(const int* __restrict__ gcurU, int BU, int* cntbU, int* ebaseU,
                             const int* __restrict__ gcurI, int BI, int* cntbI, int* ebaseI) {
    __shared__ int wsum[16];
    const int* gcur; int B; int* cntb; int* ebase;
    if (blockIdx.x == 0) { gcur = gcurU; B = BU; cntb = cntbU; ebase = ebaseU; }
    else { gcur = gcurI; B = BI; cntb = cntbI; ebase = ebaseI; }
    int t = threadIdx.x;
    int v = 0;
    if (t < B) {
        v = gcur[t * 16];
        if (v < 0) v = 0;
        if (v > CAPB) v = CAPB;
    }
    int incl = block_scan_1024(v, wsum);
    if (t < B) { cntb[t] = v; ebase[t] = incl - v; }
}

// one workgroup per bucket (U buckets then I buckets): stage records in LDS,
// count rows, scan, emit CSR
__global__ __launch_bounds__(256) void finalize_csr(
    const int2* __restrict__ binnedU, const int* __restrict__ cntbU,
    const int* __restrict__ ebaseU, int RPBU, int nu,
    int2* __restrict__ ccvU, int* __restrict__ uoff, int BU,
    const int2* __restrict__ binnedI, const int* __restrict__ cntbI,
    const int* __restrict__ ebaseI, int RPBI, int ni,
    int2* __restrict__ ccvI, int* __restrict__ ioff) {
    __shared__ int2 rec[CAPB];
    __shared__ int cnt_r[256];
    __shared__ int excl[257];
    __shared__ int curs[256];
    int b = blockIdx.x;
    const int2* binned; const int* cntb; const int* ebase; int RPB; int n;
    int2* ccv; int* off;
    if (b < BU) {
        binned = binnedU; cntb = cntbU; ebase = ebaseU; RPB = RPBU; n = nu;
        ccv = ccvU; off = uoff;
    } else {
        b -= BU;
        binned = binnedI; cntb = cntbI; ebase = ebaseI; RPB = RPBI; n = ni;
        ccv = ccvI; off = ioff;
    }
    int t = threadIdx.x;
    int r0 = b * RPB;
    int nrows = n - r0; if (nrows > RPB) nrows = RPB;
    if (nrows <= 0) return;
    int cnt = cntb[b];
    int eb  = ebase[b];
    const int2* src = binned + (size_t)b * CAPB;
    cnt_r[t] = 0;
    __syncthreads();
    for (int p = t; p < cnt; p += 256) {
        int2 r = src[p];
        rec[p] = r;
        atomicAdd(&cnt_r[(r.x >> 17) & 0xFF], 1);
    }
    __syncthreads();
    // exclusive scan of 256 counters: wave 0, 4 segments of 64 with carry
    if (t < 64) {
        int carry = 0;
#pragma unroll
        for (int seg = 0; seg < 4; ++seg) {
            int i = seg * 64 + t;
            int v = cnt_r[i];
            int s = v;
#pragma unroll
            for (int d = 1; d < 64; d <<= 1) {
                int u2 = __shfl_up(s, d);
                if (t >= d) s += u2;
            }
            excl[i] = carry + s - v;
            carry += __shfl(s, 63);
        }
        if (t == 0) excl[256] = carry;
    }
    __syncthreads();
    curs[t] = excl[t];
    if (t < nrows) off[r0 + t] = eb + excl[t];
    if (t == 0 && r0 + nrows == n) off[n] = eb + cnt;
    __syncthreads();
    for (int p = t; p < cnt; p += 256) {
        int2 r = rec[p];
        int inrow = (r.x >> 17) & 0xFF;
        int slot = atomicAdd(&curs[inrow], 1);
        ccv[eb + slot] = make_int2(r.x & 0x1FFFF, r.y);
    }
}

// ---------------- fused SPMM + MFMA dense + leaky_relu + L2 norm ----------------
// ONE 64-row tile per block (grid = ntU + ntI). Block = 4 waves; wave owns 16 rows
// in 4 passes of 4 rows; each 16-lane group owns ONE row per pass (lane q holds
// features 4q..4q+3) with an 8-deep edge pipeline -> 32 outstanding gathers/wave.
// Rows land in per-wave LDS X tile [16][72] bf16. W staged per block in LDS
// [64][72] bf16. Dense: X(16x64)@W^T via 8x mfma_f32_16x16x32_bf16. C/D layout
// (verified): col=lane&15, row=(lane>>4)*4+reg. Norm: 4-step shfl_xor butterfly.
// x and y MUST be distinct buffers.

__global__ __launch_bounds__(256, 4) void spmm_mfma(
    const int* __restrict__ uoff, const int2* __restrict__ ccvU,
    const ushort* __restrict__ xu, const float* __restrict__ Wu, const float* __restrict__ bu,
    float* __restrict__ yfu, ushort* __restrict__ ybu, int nu, int ntU,
    const int* __restrict__ ioff, const int2* __restrict__ ccvI,
    const ushort* __restrict__ xi, const float* __restrict__ Wi, const float* __restrict__ bi,
    float* __restrict__ yfi, ushort* __restrict__ ybi, int ni) {
    __shared__ ushort wt[64 * 72];       // W row-major bf16, rows padded to 72
    __shared__ ushort xt[4 * 16 * 72];   // per-wave X tiles
    int tid = threadIdx.x;
    int lane = tid & 63, wid = tid >> 6;
    int q = lane & 15, g = lane >> 4;
    int tile = blockIdx.x;
    const int* off; const int2* ccv; const ushort* x; const float* W; const float* bv;
    float* yf; ushort* yb; int n;
    if (tile < ntU) {
        off = uoff; ccv = ccvU; x = xu; W = Wu; bv = bu; yf = yfu; yb = ybu; n = nu;
    } else {
        tile -= ntU;
        off = ioff; ccv = ccvI; x = xi; W = Wi; bv = bi; yf = yfi; yb = ybi; n = ni;
    }
    // stage W: coalesced read, bf16 into padded LDS
    for (int idx = tid; idx < EMB * EMB; idx += 256) {
        int r = idx >> 6, c = idx & 63;
        wt[r * 72 + c] = bf16_rne(W[idx]);
    }
    float bias[4];
#pragma unroll
    for (int t = 0; t < 4; ++t) bias[t] = bv[16 * t + q];
    __syncthreads();

    const uint2* xv2 = (const uint2*)x;
    ushort* xw = xt + wid * (16 * 72);
    int rowW = (tile << 6) + wid * 16;   // wave's first row

    // ---- gather 16 rows into LDS X tile: 4 passes, one row per group ----
#pragma unroll
    for (int j = 0; j < 4; ++j) {
        int rr = j * 4 + g;              // tile-local row for this group
        int row = rowW + rr;
        float av[4] = {0.f, 0.f, 0.f, 0.f};
        if (row < n) {
            int s = off[row], e = off[row + 1];
            for (int p = s; p < e; p += 8) {
                int2 ed[8];
                uint2 gx[8];
#pragma unroll
                for (int k = 0; k < 8; ++k) {
                    int idx = p + k;
                    idx = (idx < e) ? idx : (e - 1);
                    ed[k] = ccv[idx];
                }
#pragma unroll
                for (int k = 0; k < 8; ++k)
                    gx[k] = xv2[(size_t)(uint)ed[k].x * 16 + q];
#pragma unroll
                for (int k = 0; k < 8; ++k) {
                    float v = (p + k < e) ? __int_as_float(ed[k].y) : 0.f;
                    av[0] = fmaf(v, __uint_as_float(gx[k].x << 16), av[0]);
                    av[1] = fmaf(v, __uint_as_float(gx[k].x & 0xffff0000u), av[1]);
                    av[2] = fmaf(v, __uint_as_float(gx[k].y << 16), av[2]);
                    av[3] = fmaf(v, __uint_as_float(gx[k].y & 0xffff0000u), av[3]);
                }
            }
        }
        // group g writes its row rr (16 lanes x 8B, conflict-free)
        uint p0 = (uint)bf16_rne(av[0]) | ((uint)bf16_rne(av[1]) << 16);
        uint p1 = (uint)bf16_rne(av[2]) | ((uint)bf16_rne(av[3]) << 16);
        *(uint2*)(xw + rr * 72 + q * 4) = make_uint2(p0, p1);
    }
    __syncthreads();   // X tiles visible (cross-lane/cross-wave)

    // ---- dense: D(16x64) = X @ W^T, 2 K-steps x 4 N-tiles ----
    f32x4 ac0 = {0.f, 0.f, 0.f, 0.f}, ac1 = ac0, ac2 = ac0, ac3 = ac0;
#pragma unroll
    for (int ks = 0; ks < 2; ++ks) {
        bf16x8 af = *(const bf16x8*)(xw + q * 72 + g * 8 + ks * 32);
        bf16x8 b0 = *(const bf16x8*)(wt + (q +  0) * 72 + g * 8 + ks * 32);
        bf16x8 b1 = *(const bf16x8*)(wt + (q + 16) * 72 + g * 8 + ks * 32);
        bf16x8 b2 = *(const bf16x8*)(wt + (q + 32) * 72 + g * 8 + ks * 32);
        bf16x8 b3 = *(const bf16x8*)(wt + (q + 48) * 72 + g * 8 + ks * 32);
        ac0 = __builtin_amdgcn_mfma_f32_16x16x32_bf16(af, b0, ac0, 0, 0, 0);
        ac1 = __builtin_amdgcn_mfma_f32_16x16x32_bf16(af, b1, ac1, 0, 0, 0);
        ac2 = __builtin_amdgcn_mfma_f32_16x16x32_bf16(af, b2, ac2, 0, 0, 0);
        ac3 = __builtin_amdgcn_mfma_f32_16x16x32_bf16(af, b3, ac3, 0, 0, 0);
    }

    // ---- bias + leaky_relu + L2 norm + store ----
    // lane holds D[row=g*4+r][col=q+16t] for t,r in 0..3
    float dv[4][4];
    float ss[4] = {0.f, 0.f, 0.f, 0.f};
#pragma unroll
    for (int t = 0; t < 4; ++t) {
        f32x4 a = (t == 0) ? ac0 : (t == 1) ? ac1 : (t == 2) ? ac2 : ac3;
#pragma unroll
        for (int r = 0; r < 4; ++r) {
            float d = a[r] + bias[t];
            d = (d > 0.f) ? d : 0.01f * d;
            dv[t][r] = d;
            ss[r] = fmaf(d, d, ss[r]);
        }
    }
#pragma unroll
    for (int r = 0; r < 4; ++r) {
        float s2 = ss[r];
        s2 += __shfl_xor(s2, 1);
        s2 += __shfl_xor(s2, 2);
        s2 += __shfl_xor(s2, 4);
        s2 += __shfl_xor(s2, 8);
        float scl = 1.0f / fmaxf(sqrtf(s2), 1e-12f);
        int orow = rowW + g * 4 + r;
        if (orow < n) {
#pragma unroll
            for (int t = 0; t < 4; ++t) {
                float outv = dv[t][r] * scl;
                size_t cidx = (size_t)orow * EMB + 16 * t + q;
                if (yb) yb[cidx] = bf16_rne(outv);
                else    yf[cidx] = outv;
            }
        }
    }
}

// ---------------- launch ----------------

extern "C" void kernel_launch(void* const* d_in, const int* in_sizes, int n_in,
                              void* d_out, int out_size, void* d_ws, size_t ws_size,
                              hipStream_t stream) {
    const float* user_emb = (const float*)d_in[0];
    const float* item_emb = (const float*)d_in[1];
    const float* Wu0 = (const float*)d_in[2];
    const float* bu0 = (const float*)d_in[3];
    const float* Wu1 = (const float*)d_in[4];
    const float* bu1 = (const float*)d_in[5];
    const float* Wi0 = (const float*)d_in[6];
    const float* bi0 = (const float*)d_in[7];
    const float* Wi1 = (const float*)d_in[8];
    const float* bi1 = (const float*)d_in[9];
    const int*   u_rows = (const int*)d_in[10];
    const int*   u_cols = (const int*)d_in[11];
    const float* u_vals = (const float*)d_in[12];
    const int*   i_rows = (const int*)d_in[13];
    const int*   i_cols = (const int*)d_in[14];
    const float* i_vals = (const float*)d_in[15];

    const int nu = in_sizes[0] / EMB;
    const int ni = in_sizes[1] / EMB;
    const int eu = in_sizes[10];
    const int ei = in_sizes[13];

    const int BU = 512, BI = 256;
    const int RPBU = (nu + BU - 1) / BU;   // 196
    const int RPBI = (ni + BI - 1) / BI;   // 196

    float* out_u = (float*)d_out;
    float* out_i = out_u + (size_t)nu * EMB;

    // workspace carve (256B aligned)
    size_t o = 0;
    char* wsb = (char*)d_ws;
    auto carve = [&](size_t bytes) -> void* {
        void* p = wsb + o;
        o += (bytes + 255) & ~(size_t)255;
        return p;
    };
    ushort* xbu0 = (ushort*)carve((size_t)nu * EMB * 2);   // bf16 cast of user_emb
    ushort* xbi0 = (ushort*)carve((size_t)ni * EMB * 2);   // bf16 cast of item_emb
    // region shared in time: binned records (CSR build) -> layer-0 bf16 outputs
    size_t binnedU_bytes = (size_t)BU * CAPB * 8;
    size_t binnedI_bytes = (size_t)BI * CAPB * 8;
    size_t xb1_bytes = ((size_t)nu + ni) * EMB * 2;
    size_t shared_bytes = binnedU_bytes + binnedI_bytes;
    if (xb1_bytes > shared_bytes) shared_bytes = xb1_bytes;
    char* regionA = (char*)carve(shared_bytes);
    int2* binnedU = (int2*)regionA;
    int2* binnedI = (int2*)(regionA + binnedU_bytes);
    ushort* xbu1 = (ushort*)regionA;                        // aliases binned (dead by then)
    ushort* xbi1 = (ushort*)(regionA + (size_t)nu * EMB * 2);
    int2* ccvU  = (int2*)carve((size_t)eu * 8);
    int2* ccvI  = (int2*)carve((size_t)ei * 8);
    int*  uoff  = (int*)carve((size_t)(nu + 1) * 4);
    int*  ioff  = (int*)carve((size_t)(ni + 1) * 4);
    int*  gcur  = (int*)carve((size_t)(BU + BI) * 16 * 4); // one memset covers both
    int*  gcurU = gcur;
    int*  gcurI = gcur + (size_t)BU * 16;
    int*  cntbU = (int*)carve((size_t)BU * 4);
    int*  ebaseU= (int*)carve((size_t)BU * 4);
    int*  cntbI = (int*)carve((size_t)BI * 4);
    int*  ebaseI= (int*)carve((size_t)BI * 4);
    (void)ws_size;

    // ---- CSR build via bucket sort + embedding cast, compacted launches ----
    hipMemsetAsync(gcur, 0, (size_t)(BU + BI) * 16 * 4, stream);
    {
        int nbU = (eu + CHUNK - 1) / CHUNK;
        int nbI = (ei + CHUNK - 1) / CHUNK;
        long n4u = (long)nu * EMB / 4, n4i = (long)ni * EMB / 4;
        int nbCast = (int)((n4u + n4i + 1023) / 1024);
        prep<<<nbU + nbI + nbCast, 256, 0, stream>>>(
            u_rows, u_cols, u_vals, eu, BU, RPBU, gcurU, binnedU, nbU,
            i_rows, i_cols, i_vals, ei, BI, RPBI, gcurI, binnedI, nbI,
            (const float4*)user_emb, xbu0, n4u,
            (const float4*)item_emb, xbi0, n4i, nbCast);
    }
    scan_buckets<<<2, 1024, 0, stream>>>(gcurU, BU, cntbU, ebaseU,
                                         gcurI, BI, cntbI, ebaseI);
    finalize_csr<<<BU + BI, 256, 0, stream>>>(
        binnedU, cntbU, ebaseU, RPBU, nu, ccvU, uoff, BU,
        binnedI, cntbI, ebaseI, RPBI, ni, ccvI, ioff);

    // ---- 2 GCN layers, fused per layer; ping-pong bf16 buffers ----
    int ntU = (nu + 63) >> 6, ntI = (ni + 63) >> 6;
    // layer 0: bf16(emb) -> bf16 tmp (tmp aliases binned, which is dead now)
    spmm_mfma<<<ntU + ntI, 256, 0, stream>>>(
        uoff, ccvU, xbu0, Wu0, bu0, nullptr, xbu1, nu, ntU,
        ioff, ccvI, xbi0, Wi0, bi0, nullptr, xbi1, ni);
    // layer 1: bf16 tmp -> f32 out
    spmm_mfma<<<ntU + ntI, 256, 0, stream>>>(
        uoff, ccvU, xbu1, Wu1, bu1, out_u, nullptr, nu, ntU,
        ioff, ccvI, xbi1, Wi1, bi1, out_i, nullptr, ni);
}

// Round 13
// 190.740 us; speedup vs baseline: 5.9484x; 1.0236x over previous
//
#include <hip/hip_runtime.h>
#include <hip/hip_bf16.h>
#include <math.h>

#define EMB 64
#define CAPB 3584      // per-bucket slot capacity (mean 3125, sigma ~56 -> 8.2 sigma)
#define CHUNK 4096     // edges per bin block

typedef __attribute__((ext_vector_type(8))) short bf16x8;
typedef __attribute__((ext_vector_type(4))) float f32x4;

__device__ __forceinline__ ushort bf16_rne(float f) {
    uint u = __float_as_uint(f);
    return (ushort)((u + 0x7fffu + ((u >> 16) & 1u)) >> 16);
}

// ---------------- prep kernel: bin_edges(U) | bin_edges(I) | cast_bf16 ----------------
// gcur assumed zeroed (hipMemsetAsync). Record: int2(col | inrow<<17, f32val).
// Binned writes are LDS-staged in bucket-sorted order -> coalesced full-line runs.

__device__ __forceinline__ void bin_body(
    const int* __restrict__ rows, const int* __restrict__ cols,
    const float* __restrict__ vals, int nE, int B, int RPB,
    int* gcur, int2* __restrict__ binned, int blk,
    int* cnt, int* sstart, int* lbase, int2* rec, ushort* bkt) {
    int t = threadIdx.x;
    for (int i = t; i < B; i += 256) cnt[i] = 0;
    __syncthreads();
    int c0 = blk * CHUNK;
    int ntot = nE - c0; if (ntot > CHUNK) ntot = CHUNK;
    int bs[16];
#pragma unroll
    for (int j = 0; j < 16; ++j) {
        int idx = c0 + t + j * 256;
        int bsv = -1;
        if (idx < nE) {
            int row = rows[idx];
            int b = row / RPB;
            int inrow = row - b * RPB;
            int slot = atomicAdd(&cnt[b], 1);
            bsv = (b << 21) | (inrow << 13) | slot;   // b<512, inrow<256, slot<8192
        }
        bs[j] = bsv;
    }
    __syncthreads();
    // reserve global runs per bucket
    for (int i = t; i < B; i += 256) {
        int c = cnt[i];
        lbase[i] = c ? atomicAdd(&gcur[i * 16], c) : 0;
    }
    // exclusive scan of cnt -> sstart (wave 0, B/64 segments with carry)
    if (t < 64) {
        int carry = 0;
        int nseg = B >> 6;
        for (int seg = 0; seg < nseg; ++seg) {
            int i = seg * 64 + t;
            int v = cnt[i];
            int s = v;
#pragma unroll
            for (int d = 1; d < 64; d <<= 1) {
                int u2 = __shfl_up(s, d);
                if (t >= d) s += u2;
            }
            sstart[i] = carry + s - v;
            carry += __shfl(s, 63);
        }
    }
    __syncthreads();
    // stage records into LDS in bucket-sorted order
#pragma unroll
    for (int j = 0; j < 16; ++j) {
        int idx = c0 + t + j * 256;
        if (idx >= nE) continue;
        int bsv = bs[j];
        int b = bsv >> 21, inrow = (bsv >> 13) & 0xFF, slot = bsv & 0x1FFF;
        int col = cols[idx];
        float v = vals[idx];
        int li = sstart[b] + slot;
        rec[li] = make_int2(col | (inrow << 17), __float_as_int(v));
        bkt[li] = (ushort)b;
    }
    __syncthreads();
    // coalesced copy: consecutive i in a bucket -> consecutive global dest
    for (int i = t; i < ntot; i += 256) {
        int b = bkt[i];
        int pos = lbase[b] + (i - sstart[b]);
        if (pos < CAPB)
            binned[(size_t)b * CAPB + pos] = rec[i];
    }
}

__global__ __launch_bounds__(256) void prep(
    const int* __restrict__ u_rows, const int* __restrict__ u_cols,
    const float* __restrict__ u_vals, int eu, int BU, int RPBU,
    int* gcurU, int2* __restrict__ binnedU, int nbU,
    const int* __restrict__ i_rows, const int* __restrict__ i_cols,
    const float* __restrict__ i_vals, int ei, int BI, int RPBI,
    int* gcurI, int2* __restrict__ binnedI, int nbI,
    const float4* __restrict__ embU, ushort* __restrict__ xbU, long n4u,
    const float4* __restrict__ embI, ushort* __restrict__ xbI, long n4i,
    int nbCast) {
    __shared__ int2 rec[CHUNK];        // 32 KB
    __shared__ ushort bkt[CHUNK];      // 8 KB
    __shared__ int cnt[512];
    __shared__ int sstart[512];
    __shared__ int lbase[512];
    int b = blockIdx.x;
    if (b < nbU) {
        bin_body(u_rows, u_cols, u_vals, eu, BU, RPBU, gcurU, binnedU, b,
                 cnt, sstart, lbase, rec, bkt);
        return;
    }
    b -= nbU;
    if (b < nbI) {
        bin_body(i_rows, i_cols, i_vals, ei, BI, RPBI, gcurI, binnedI, b,
                 cnt, sstart, lbase, rec, bkt);
        return;
    }
    b -= nbI;
    // cast: 4 float4 per thread, strided
    long tot = n4u + n4i;
    long base = (long)b * 1024 + threadIdx.x;
#pragma unroll
    for (int k = 0; k < 4; ++k) {
        long i = base + k * 256;
        if (i >= tot) return;
        const float4* a; ushort* o; long j;
        if (i < n4u) { a = embU; o = xbU; j = i; }
        else { a = embI; o = xbI; j = i - n4u; }
        float4 v = a[j];
        ushort4 r;
        r.x = bf16_rne(v.x); r.y = bf16_rne(v.y); r.z = bf16_rne(v.z); r.w = bf16_rne(v.w);
        *(ushort4*)(o + j * 4) = r;
    }
}

// ---------------- finalize: in-place bucket sort -> CSR (binned becomes ccv) ----------
// One workgroup per bucket (U buckets then I buckets). Reads its bucket's records,
// counts rows, scans, writes per-row int2(start,end) offsets and the row-sorted,
// col-masked records back into binned IN PLACE. No separate ccv buffer, no
// scan_buckets kernel (count read directly from gcur).

__global__ __launch_bounds__(256) void finalize_csr(
    int2* __restrict__ binnedU, const int* __restrict__ gcurU, int RPBU, int nu,
    int2* __restrict__ offseU, int BU,
    int2* __restrict__ binnedI, const int* __restrict__ gcurI, int RPBI, int ni,
    int2* __restrict__ offseI) {
    __shared__ int2 rec[CAPB];
    __shared__ int cnt_r[256];
    __shared__ int excl[257];
    __shared__ int curs[256];
    int b = blockIdx.x;
    int2* binned; const int* gcur; int RPB; int n; int2* offse;
    if (b < BU) {
        binned = binnedU; gcur = gcurU; RPB = RPBU; n = nu; offse = offseU;
    } else {
        b -= BU;
        binned = binnedI; gcur = gcurI; RPB = RPBI; n = ni; offse = offseI;
    }
    int t = threadIdx.x;
    int r0 = b * RPB;
    int nrows = n - r0; if (nrows > RPB) nrows = RPB;
    if (nrows <= 0) return;
    int cnt = gcur[b * 16];
    if (cnt > CAPB) cnt = CAPB;
    int2* src = binned + (size_t)b * CAPB;
    int B0 = b * CAPB;
    cnt_r[t] = 0;
    __syncthreads();
    for (int p = t; p < cnt; p += 256) {
        int2 r = src[p];
        rec[p] = r;
        atomicAdd(&cnt_r[(r.x >> 17) & 0xFF], 1);
    }
    __syncthreads();
    // exclusive scan of 256 counters: wave 0, 4 segments of 64 with carry
    if (t < 64) {
        int carry = 0;
#pragma unroll
        for (int seg = 0; seg < 4; ++seg) {
            int i = seg * 64 + t;
            int v = cnt_r[i];
            int s = v;
#pragma unroll
            for (int d = 1; d < 64; d <<= 1) {
                int u2 = __shfl_up(s, d);
                if (t >= d) s += u2;
            }
            excl[i] = carry + s - v;
            carry += __shfl(s, 63);
        }
        if (t == 0) excl[256] = carry;
    }
    __syncthreads();
    curs[t] = excl[t];
    if (t < nrows) offse[r0 + t] = make_int2(B0 + excl[t], B0 + excl[t + 1]);
    __syncthreads();
    for (int p = t; p < cnt; p += 256) {
        int2 r = rec[p];
        int inrow = (r.x >> 17) & 0xFF;
        int slot = atomicAdd(&curs[inrow], 1);
        src[slot] = make_int2(r.x & 0x1FFFF, r.y);
    }
}

// ---------------- fused SPMM + MFMA dense + leaky_relu + L2 norm ----------------
// ONE 64-row tile per block (grid = ntU + ntI). Block = 4 waves; wave owns 16 rows
// in 4 passes of 4 rows; each 16-lane group owns ONE row per pass (lane q holds
// features 4q..4q+3) with an 8-deep edge pipeline -> 32 outstanding gathers/wave.
// Rows land in per-wave LDS X tile [16][72] bf16. W staged per block in LDS
// [64][72] bf16. Dense: X(16x64)@W^T via 8x mfma_f32_16x16x32_bf16. C/D layout
// (verified): col=lane&15, row=(lane>>4)*4+reg. Norm: 4-step shfl_xor butterfly.
// offse[row] = int2(start, end) into the in-place-sorted binned records.
// 6 blocks/CU (VGPR=32, LDS 18KB): 24 waves/CU for gather-latency hiding.
// x and y MUST be distinct buffers.

__global__ __launch_bounds__(256, 6) void spmm_mfma(
    const int2* __restrict__ offseU, const int2* __restrict__ ccvU,
    const ushort* __restrict__ xu, const float* __restrict__ Wu, const float* __restrict__ bu,
    float* __restrict__ yfu, ushort* __restrict__ ybu, int nu, int ntU,
    const int2* __restrict__ offseI, const int2* __restrict__ ccvI,
    const ushort* __restrict__ xi, const float* __restrict__ Wi, const float* __restrict__ bi,
    float* __restrict__ yfi, ushort* __restrict__ ybi, int ni) {
    __shared__ ushort wt[64 * 72];       // W row-major bf16, rows padded to 72
    __shared__ ushort xt[4 * 16 * 72];   // per-wave X tiles
    int tid = threadIdx.x;
    int lane = tid & 63, wid = tid >> 6;
    int q = lane & 15, g = lane >> 4;
    int tile = blockIdx.x;
    const int2* offse; const int2* ccv; const ushort* x; const float* W; const float* bv;
    float* yf; ushort* yb; int n;
    if (tile < ntU) {
        offse = offseU; ccv = ccvU; x = xu; W = Wu; bv = bu; yf = yfu; yb = ybu; n = nu;
    } else {
        tile -= ntU;
        offse = offseI; ccv = ccvI; x = xi; W = Wi; bv = bi; yf = yfi; yb = ybi; n = ni;
    }
    // stage W: coalesced read, bf16 into padded LDS
    for (int idx = tid; idx < EMB * EMB; idx += 256) {
        int r = idx >> 6, c = idx & 63;
        wt[r * 72 + c] = bf16_rne(W[idx]);
    }
    float bias[4];
#pragma unroll
    for (int t = 0; t < 4; ++t) bias[t] = bv[16 * t + q];
    __syncthreads();

    const uint2* xv2 = (const uint2*)x;
    ushort* xw = xt + wid * (16 * 72);
    int rowW = (tile << 6) + wid * 16;   // wave's first row

    // ---- gather 16 rows into LDS X tile: 4 passes, one row per group ----
#pragma unroll
    for (int j = 0; j < 4; ++j) {
        int rr = j * 4 + g;              // tile-local row for this group
        int row = rowW + rr;
        float av[4] = {0.f, 0.f, 0.f, 0.f};
        if (row < n) {
            int2 se = offse[row];
            int s = se.x, e = se.y;
            for (int p = s; p < e; p += 8) {
                int2 ed[8];
                uint2 gx[8];
#pragma unroll
                for (int k = 0; k < 8; ++k) {
                    int idx = p + k;
                    idx = (idx < e) ? idx : (e - 1);
                    ed[k] = ccv[idx];
                }
#pragma unroll
                for (int k = 0; k < 8; ++k)
                    gx[k] = xv2[(size_t)(uint)ed[k].x * 16 + q];
#pragma unroll
                for (int k = 0; k < 8; ++k) {
                    float v = (p + k < e) ? __int_as_float(ed[k].y) : 0.f;
                    av[0] = fmaf(v, __uint_as_float(gx[k].x << 16), av[0]);
                    av[1] = fmaf(v, __uint_as_float(gx[k].x & 0xffff0000u), av[1]);
                    av[2] = fmaf(v, __uint_as_float(gx[k].y << 16), av[2]);
                    av[3] = fmaf(v, __uint_as_float(gx[k].y & 0xffff0000u), av[3]);
                }
            }
        }
        // group g writes its row rr (16 lanes x 8B, conflict-free)
        uint p0 = (uint)bf16_rne(av[0]) | ((uint)bf16_rne(av[1]) << 16);
        uint p1 = (uint)bf16_rne(av[2]) | ((uint)bf16_rne(av[3]) << 16);
        *(uint2*)(xw + rr * 72 + q * 4) = make_uint2(p0, p1);
    }
    __syncthreads();   // X tiles visible (cross-lane/cross-wave)

    // ---- dense: D(16x64) = X @ W^T, 2 K-steps x 4 N-tiles ----
    f32x4 ac0 = {0.f, 0.f, 0.f, 0.f}, ac1 = ac0, ac2 = ac0, ac3 = ac0;
#pragma unroll
    for (int ks = 0; ks < 2; ++ks) {
        bf16x8 af = *(const bf16x8*)(xw + q * 72 + g * 8 + ks * 32);
        bf16x8 b0 = *(const bf16x8*)(wt + (q +  0) * 72 + g * 8 + ks * 32);
        bf16x8 b1 = *(const bf16x8*)(wt + (q + 16) * 72 + g * 8 + ks * 32);
        bf16x8 b2 = *(const bf16x8*)(wt + (q + 32) * 72 + g * 8 + ks * 32);
        bf16x8 b3 = *(const bf16x8*)(wt + (q + 48) * 72 + g * 8 + ks * 32);
        ac0 = __builtin_amdgcn_mfma_f32_16x16x32_bf16(af, b0, ac0, 0, 0, 0);
        ac1 = __builtin_amdgcn_mfma_f32_16x16x32_bf16(af, b1, ac1, 0, 0, 0);
        ac2 = __builtin_amdgcn_mfma_f32_16x16x32_bf16(af, b2, ac2, 0, 0, 0);
        ac3 = __builtin_amdgcn_mfma_f32_16x16x32_bf16(af, b3, ac3, 0, 0, 0);
    }

    // ---- bias + leaky_relu + L2 norm + store ----
    // lane holds D[row=g*4+r][col=q+16t] for t,r in 0..3
    float dv[4][4];
    float ss[4] = {0.f, 0.f, 0.f, 0.f};
#pragma unroll
    for (int t = 0; t < 4; ++t) {
        f32x4 a = (t == 0) ? ac0 : (t == 1) ? ac1 : (t == 2) ? ac2 : ac3;
#pragma unroll
        for (int r = 0; r < 4; ++r) {
            float d = a[r] + bias[t];
            d = (d > 0.f) ? d : 0.01f * d;
            dv[t][r] = d;
            ss[r] = fmaf(d, d, ss[r]);
        }
    }
#pragma unroll
    for (int r = 0; r < 4; ++r) {
        float s2 = ss[r];
        s2 += __shfl_xor(s2, 1);
        s2 += __shfl_xor(s2, 2);
        s2 += __shfl_xor(s2, 4);
        s2 += __shfl_xor(s2, 8);
        float scl = 1.0f / fmaxf(sqrtf(s2), 1e-12f);
        int orow = rowW + g * 4 + r;
        if (orow < n) {
#pragma unroll
            for (int t = 0; t < 4; ++t) {
                float outv = dv[t][r] * scl;
                size_t cidx = (size_t)orow * EMB + 16 * t + q;
                if (yb) yb[cidx] = bf16_rne(outv);
                else    yf[cidx] = outv;
            }
        }
    }
}

// ---------------- launch ----------------

extern "C" void kernel_launch(void* const* d_in, const int* in_sizes, int n_in,
                              void* d_out, int out_size, void* d_ws, size_t ws_size,
                              hipStream_t stream) {
    const float* user_emb = (const float*)d_in[0];
    const float* item_emb = (const float*)d_in[1];
    const float* Wu0 = (const float*)d_in[2];
    const float* bu0 = (const float*)d_in[3];
    const float* Wu1 = (const float*)d_in[4];
    const float* bu1 = (const float*)d_in[5];
    const float* Wi0 = (const float*)d_in[6];
    const float* bi0 = (const float*)d_in[7];
    const float* Wi1 = (const float*)d_in[8];
    const float* bi1 = (const float*)d_in[9];
    const int*   u_rows = (const int*)d_in[10];
    const int*   u_cols = (const int*)d_in[11];
    const float* u_vals = (const float*)d_in[12];
    const int*   i_rows = (const int*)d_in[13];
    const int*   i_cols = (const int*)d_in[14];
    const float* i_vals = (const float*)d_in[15];

    const int nu = in_sizes[0] / EMB;
    const int ni = in_sizes[1] / EMB;
    const int eu = in_sizes[10];
    const int ei = in_sizes[13];

    const int BU = 512, BI = 256;
    const int RPBU = (nu + BU - 1) / BU;   // 196
    const int RPBI = (ni + BI - 1) / BI;   // 196

    float* out_u = (float*)d_out;
    float* out_i = out_u + (size_t)nu * EMB;

    // workspace carve (256B aligned)
    size_t o = 0;
    char* wsb = (char*)d_ws;
    auto carve = [&](size_t bytes) -> void* {
        void* p = wsb + o;
        o += (bytes + 255) & ~(size_t)255;
        return p;
    };
    ushort* xbu0 = (ushort*)carve((size_t)nu * EMB * 2);   // bf16 cast of user_emb
    ushort* xbi0 = (ushort*)carve((size_t)ni * EMB * 2);   // bf16 cast of item_emb
    int2* binnedU = (int2*)carve((size_t)BU * CAPB * 8);   // becomes CSR records in place
    int2* binnedI = (int2*)carve((size_t)BI * CAPB * 8);
    ushort* xbu1 = (ushort*)carve((size_t)nu * EMB * 2);   // layer-0 outputs (bf16)
    ushort* xbi1 = (ushort*)carve((size_t)ni * EMB * 2);
    int2* offseU = (int2*)carve((size_t)nu * 8);           // per-row (start,end)
    int2* offseI = (int2*)carve((size_t)ni * 8);
    int*  gcur  = (int*)carve((size_t)(BU + BI) * 16 * 4); // one memset covers both
    int*  gcurU = gcur;
    int*  gcurI = gcur + (size_t)BU * 16;
    (void)ws_size;

    // ---- CSR build via bucket sort + embedding cast, compacted launches ----
    hipMemsetAsync(gcur, 0, (size_t)(BU + BI) * 16 * 4, stream);
    {
        int nbU = (eu + CHUNK - 1) / CHUNK;
        int nbI = (ei + CHUNK - 1) / CHUNK;
        long n4u = (long)nu * EMB / 4, n4i = (long)ni * EMB / 4;
        int nbCast = (int)((n4u + n4i + 1023) / 1024);
        prep<<<nbU + nbI + nbCast, 256, 0, stream>>>(
            u_rows, u_cols, u_vals, eu, BU, RPBU, gcurU, binnedU, nbU,
            i_rows, i_cols, i_vals, ei, BI, RPBI, gcurI, binnedI, nbI,
            (const float4*)user_emb, xbu0, n4u,
            (const float4*)item_emb, xbi0, n4i, nbCast);
    }
    finalize_csr<<<BU + BI, 256, 0, stream>>>(
        binnedU, gcurU, RPBU, nu, offseU, BU,
        binnedI, gcurI, RPBI, ni, offseI);

    // ---- 2 GCN layers, fused per layer; ping-pong bf16 buffers ----
    int ntU = (nu + 63) >> 6, ntI = (ni + 63) >> 6;
    // layer 0: bf16(emb) -> bf16 tmp
    spmm_mfma<<<ntU + ntI, 256, 0, stream>>>(
        offseU, binnedU, xbu0, Wu0, bu0, nullptr, xbu1, nu, ntU,
        offseI, binnedI, xbi0, Wi0, bi0, nullptr, xbi1, ni);
    // layer 1: bf16 tmp -> f32 out
    spmm_mfma<<<ntU + ntI, 256, 0, stream>>>(
        offseU, binnedU, xbu1, Wu1, bu1, out_u, nullptr, nu, ntU,
        offseI, binnedI, xbi1, Wi1, bi1, out_i, nullptr, ni);
}

// Round 14
// 188.396 us; speedup vs baseline: 6.0224x; 1.0124x over previous
//
#include <hip/hip_runtime.h>
#include <hip/hip_bf16.h>
#include <math.h>

#define EMB 64
#define CAPB 3584      // per-bucket slot capacity (mean 3125, sigma ~56 -> 8.2 sigma)
#define CHUNK 4096     // edges per bin block

typedef __attribute__((ext_vector_type(8))) short bf16x8;
typedef __attribute__((ext_vector_type(4))) float f32x4;

__device__ __forceinline__ ushort bf16_rne(float f) {
    uint u = __float_as_uint(f);
    return (ushort)((u + 0x7fffu + ((u >> 16) & 1u)) >> 16);
}

__device__ __forceinline__ uint bf16_pack2(float a, float b) {
    return (uint)bf16_rne(a) | ((uint)bf16_rne(b) << 16);
}

// ---------------- prep kernel: bin(U) | bin(I) | cast_bf16 | pack W ----------------
// gcur assumed zeroed (hipMemsetAsync). Record: int2(col | inrow<<17, f32val).
// Binned writes are LDS-staged in bucket-sorted order -> coalesced full-line runs.

__device__ __forceinline__ void bin_body(
    const int* __restrict__ rows, const int* __restrict__ cols,
    const float* __restrict__ vals, int nE, int B, int RPB,
    int* gcur, int2* __restrict__ binned, int blk,
    int* cnt, int* sstart, int* lbase, int2* rec, ushort* bkt) {
    int t = threadIdx.x;
    for (int i = t; i < B; i += 256) cnt[i] = 0;
    __syncthreads();
    int c0 = blk * CHUNK;
    int ntot = nE - c0; if (ntot > CHUNK) ntot = CHUNK;
    int bs[16];
#pragma unroll
    for (int j = 0; j < 16; ++j) {
        int idx = c0 + t + j * 256;
        int bsv = -1;
        if (idx < nE) {
            int row = rows[idx];
            int b = row / RPB;
            int inrow = row - b * RPB;
            int slot = atomicAdd(&cnt[b], 1);
            bsv = (b << 21) | (inrow << 13) | slot;   // b<512, inrow<256, slot<8192
        }
        bs[j] = bsv;
    }
    __syncthreads();
    // reserve global runs per bucket
    for (int i = t; i < B; i += 256) {
        int c = cnt[i];
        lbase[i] = c ? atomicAdd(&gcur[i * 16], c) : 0;
    }
    // exclusive scan of cnt -> sstart (wave 0, B/64 segments with carry)
    if (t < 64) {
        int carry = 0;
        int nseg = B >> 6;
        for (int seg = 0; seg < nseg; ++seg) {
            int i = seg * 64 + t;
            int v = cnt[i];
            int s = v;
#pragma unroll
            for (int d = 1; d < 64; d <<= 1) {
                int u2 = __shfl_up(s, d);
                if (t >= d) s += u2;
            }
            sstart[i] = carry + s - v;
            carry += __shfl(s, 63);
        }
    }
    __syncthreads();
    // stage records into LDS in bucket-sorted order
#pragma unroll
    for (int j = 0; j < 16; ++j) {
        int idx = c0 + t + j * 256;
        if (idx >= nE) continue;
        int bsv = bs[j];
        int b = bsv >> 21, inrow = (bsv >> 13) & 0xFF, slot = bsv & 0x1FFF;
        int col = cols[idx];
        float v = vals[idx];
        int li = sstart[b] + slot;
        rec[li] = make_int2(col | (inrow << 17), __float_as_int(v));
        bkt[li] = (ushort)b;
    }
    __syncthreads();
    // coalesced copy: consecutive i in a bucket -> consecutive global dest
    for (int i = t; i < ntot; i += 256) {
        int b = bkt[i];
        int pos = lbase[b] + (i - sstart[b]);
        if (pos < CAPB)
            binned[(size_t)b * CAPB + pos] = rec[i];
    }
}

__global__ __launch_bounds__(256) void prep(
    const int* __restrict__ u_rows, const int* __restrict__ u_cols,
    const float* __restrict__ u_vals, int eu, int BU, int RPBU,
    int* gcurU, int2* __restrict__ binnedU, int nbU,
    const int* __restrict__ i_rows, const int* __restrict__ i_cols,
    const float* __restrict__ i_vals, int ei, int BI, int RPBI,
    int* gcurI, int2* __restrict__ binnedI, int nbI,
    const float4* __restrict__ embU, ushort* __restrict__ xbU, long n4u,
    const float4* __restrict__ embI, ushort* __restrict__ xbI, long n4i,
    int nbCast,
    const float4* __restrict__ W0s, ushort* __restrict__ W0d,
    const float4* __restrict__ W1s, ushort* __restrict__ W1d,
    const float4* __restrict__ W2s, ushort* __restrict__ W2d,
    const float4* __restrict__ W3s, ushort* __restrict__ W3d) {
    __shared__ int2 rec[CHUNK];        // 32 KB
    __shared__ ushort bkt[CHUNK];      // 8 KB
    __shared__ int cnt[512];
    __shared__ int sstart[512];
    __shared__ int lbase[512];
    int b = blockIdx.x;
    if (b < nbU) {
        bin_body(u_rows, u_cols, u_vals, eu, BU, RPBU, gcurU, binnedU, b,
                 cnt, sstart, lbase, rec, bkt);
        return;
    }
    b -= nbU;
    if (b < nbI) {
        bin_body(i_rows, i_cols, i_vals, ei, BI, RPBI, gcurI, binnedI, b,
                 cnt, sstart, lbase, rec, bkt);
        return;
    }
    b -= nbI;
    if (b < nbCast) {
        // cast: 4 float4 per thread, strided
        long tot = n4u + n4i;
        long base = (long)b * 1024 + threadIdx.x;
#pragma unroll
        for (int k = 0; k < 4; ++k) {
            long i = base + k * 256;
            if (i >= tot) return;
            const float4* a; ushort* o; long j;
            if (i < n4u) { a = embU; o = xbU; j = i; }
            else { a = embI; o = xbI; j = i - n4u; }
            float4 v = a[j];
            ushort4 r;
            r.x = bf16_rne(v.x); r.y = bf16_rne(v.y); r.z = bf16_rne(v.z); r.w = bf16_rne(v.w);
            *(ushort4*)(o + j * 4) = r;
        }
        return;
    }
    b -= nbCast;
    // pack one 64x64 W matrix to bf16 (16 contiguous elems per thread)
    {
        const float4* src = (b == 0) ? W0s : (b == 1) ? W1s : (b == 2) ? W2s : W3s;
        ushort* dst = (b == 0) ? W0d : (b == 1) ? W1d : (b == 2) ? W2d : W3d;
        int t = threadIdx.x;
        float4 v0 = src[t * 4 + 0], v1 = src[t * 4 + 1];
        float4 v2 = src[t * 4 + 2], v3 = src[t * 4 + 3];
        uint4 o0, o1;
        o0.x = bf16_pack2(v0.x, v0.y); o0.y = bf16_pack2(v0.z, v0.w);
        o0.z = bf16_pack2(v1.x, v1.y); o0.w = bf16_pack2(v1.z, v1.w);
        o1.x = bf16_pack2(v2.x, v2.y); o1.y = bf16_pack2(v2.z, v2.w);
        o1.z = bf16_pack2(v3.x, v3.y); o1.w = bf16_pack2(v3.z, v3.w);
        ((uint4*)dst)[t * 2 + 0] = o0;
        ((uint4*)dst)[t * 2 + 1] = o1;
    }
}

// ---------------- finalize: in-place bucket sort -> CSR (binned becomes ccv) ----------
// One workgroup per bucket (U buckets then I buckets). Reads its bucket's records,
// counts rows, scans, writes per-row int2(start,end) offsets and the row-sorted,
// col-masked records back into binned IN PLACE.

__global__ __launch_bounds__(256) void finalize_csr(
    int2* __restrict__ binnedU, const int* __restrict__ gcurU, int RPBU, int nu,
    int2* __restrict__ offseU, int BU,
    int2* __restrict__ binnedI, const int* __restrict__ gcurI, int RPBI, int ni,
    int2* __restrict__ offseI) {
    __shared__ int2 rec[CAPB];
    __shared__ int cnt_r[256];
    __shared__ int excl[257];
    __shared__ int curs[256];
    int b = blockIdx.x;
    int2* binned; const int* gcur; int RPB; int n; int2* offse;
    if (b < BU) {
        binned = binnedU; gcur = gcurU; RPB = RPBU; n = nu; offse = offseU;
    } else {
        b -= BU;
        binned = binnedI; gcur = gcurI; RPB = RPBI; n = ni; offse = offseI;
    }
    int t = threadIdx.x;
    int r0 = b * RPB;
    int nrows = n - r0; if (nrows > RPB) nrows = RPB;
    if (nrows <= 0) return;
    int cnt = gcur[b * 16];
    if (cnt > CAPB) cnt = CAPB;
    int2* src = binned + (size_t)b * CAPB;
    int B0 = b * CAPB;
    cnt_r[t] = 0;
    __syncthreads();
    for (int p = t; p < cnt; p += 256) {
        int2 r = src[p];
        rec[p] = r;
        atomicAdd(&cnt_r[(r.x >> 17) & 0xFF], 1);
    }
    __syncthreads();
    // exclusive scan of 256 counters: wave 0, 4 segments of 64 with carry
    if (t < 64) {
        int carry = 0;
#pragma unroll
        for (int seg = 0; seg < 4; ++seg) {
            int i = seg * 64 + t;
            int v = cnt_r[i];
            int s = v;
#pragma unroll
            for (int d = 1; d < 64; d <<= 1) {
                int u2 = __shfl_up(s, d);
                if (t >= d) s += u2;
            }
            excl[i] = carry + s - v;
            carry += __shfl(s, 63);
        }
        if (t == 0) excl[256] = carry;
    }
    __syncthreads();
    curs[t] = excl[t];
    if (t < nrows) offse[r0 + t] = make_int2(B0 + excl[t], B0 + excl[t + 1]);
    __syncthreads();
    for (int p = t; p < cnt; p += 256) {
        int2 r = rec[p];
        int inrow = (r.x >> 17) & 0xFF;
        int slot = atomicAdd(&curs[inrow], 1);
        src[slot] = make_int2(r.x & 0x1FFFF, r.y);
    }
}

// ---------------- fused SPMM + MFMA dense + leaky_relu + L2 norm ----------------
// ONE 64-row tile per block (grid = ntU + ntI). Block = 4 waves; wave owns 16 rows
// in 4 passes of 4 rows; each 16-lane group owns ONE row per pass with an 8-deep
// edge pipeline -> 32 outstanding gathers per wave. Rows land in per-wave LDS
// X tile [16][72] bf16. W is PRE-PACKED bf16 in global: staged via 2x16B vector
// load + 2x ds_write_b128 per thread (no per-block f32->bf16 conversion — that
// was ~44% of all VALU issue in rounds 11-13). Dense: X(16x64)@W^T via 8x
// mfma_f32_16x16x32_bf16. C/D layout (verified): col=lane&15, row=(lane>>4)*4+reg.
// Norm: 4-step shfl_xor butterfly. x and y MUST be distinct buffers.

__global__ __launch_bounds__(256, 6) void spmm_mfma(
    const int2* __restrict__ offseU, const int2* __restrict__ ccvU,
    const ushort* __restrict__ xu, const ushort* __restrict__ Wu, const float* __restrict__ bu,
    float* __restrict__ yfu, ushort* __restrict__ ybu, int nu, int ntU,
    const int2* __restrict__ offseI, const int2* __restrict__ ccvI,
    const ushort* __restrict__ xi, const ushort* __restrict__ Wi, const float* __restrict__ bi,
    float* __restrict__ yfi, ushort* __restrict__ ybi, int ni) {
    __shared__ ushort wt[64 * 72];       // W row-major bf16, rows padded to 72
    __shared__ ushort xt[4 * 16 * 72];   // per-wave X tiles
    int tid = threadIdx.x;
    int lane = tid & 63, wid = tid >> 6;
    int q = lane & 15, g = lane >> 4;
    int tile = blockIdx.x;
    const int2* offse; const int2* ccv; const ushort* x; const ushort* W; const float* bv;
    float* yf; ushort* yb; int n;
    if (tile < ntU) {
        offse = offseU; ccv = ccvU; x = xu; W = Wu; bv = bu; yf = yfu; yb = ybu; n = nu;
    } else {
        tile -= ntU;
        offse = offseI; ccv = ccvI; x = xi; W = Wi; bv = bi; yf = yfi; yb = ybi; n = ni;
    }
    // stage W: thread t copies elements [t*16, t*16+16) -> row r=t/4, col (t%4)*16
    {
        int r = tid >> 2, c = (tid & 3) * 16;
        uint4 v0 = ((const uint4*)W)[tid * 2 + 0];
        uint4 v1 = ((const uint4*)W)[tid * 2 + 1];
        *(uint4*)(wt + r * 72 + c) = v0;
        *(uint4*)(wt + r * 72 + c + 8) = v1;
    }
    float bias[4];
#pragma unroll
    for (int t = 0; t < 4; ++t) bias[t] = bv[16 * t + q];
    __syncthreads();

    const uint2* xv2 = (const uint2*)x;
    ushort* xw = xt + wid * (16 * 72);
    int rowW = (tile << 6) + wid * 16;   // wave's first row

    // ---- gather 16 rows into LDS X tile: 4 passes, one row per group ----
#pragma unroll
    for (int j = 0; j < 4; ++j) {
        int rr = j * 4 + g;              // tile-local row for this group
        int row = rowW + rr;
        float av[4] = {0.f, 0.f, 0.f, 0.f};
        if (row < n) {
            int2 se = offse[row];
            int s = se.x, e = se.y;
            for (int p = s; p < e; p += 8) {
                int2 ed[8];
                uint2 gx[8];
#pragma unroll
                for (int k = 0; k < 8; ++k) {
                    int idx = p + k;
                    idx = (idx < e) ? idx : (e - 1);
                    ed[k] = ccv[idx];
                }
#pragma unroll
                for (int k = 0; k < 8; ++k)
                    gx[k] = xv2[(size_t)(uint)ed[k].x * 16 + q];
#pragma unroll
                for (int k = 0; k < 8; ++k) {
                    float v = (p + k < e) ? __int_as_float(ed[k].y) : 0.f;
                    av[0] = fmaf(v, __uint_as_float(gx[k].x << 16), av[0]);
                    av[1] = fmaf(v, __uint_as_float(gx[k].x & 0xffff0000u), av[1]);
                    av[2] = fmaf(v, __uint_as_float(gx[k].y << 16), av[2]);
                    av[3] = fmaf(v, __uint_as_float(gx[k].y & 0xffff0000u), av[3]);
                }
            }
        }
        // group g writes its row rr (16 lanes x 8B, conflict-free)
        uint p0 = (uint)bf16_rne(av[0]) | ((uint)bf16_rne(av[1]) << 16);
        uint p1 = (uint)bf16_rne(av[2]) | ((uint)bf16_rne(av[3]) << 16);
        *(uint2*)(xw + rr * 72 + q * 4) = make_uint2(p0, p1);
    }
    __syncthreads();   // X tiles visible (cross-lane/cross-wave)

    // ---- dense: D(16x64) = X @ W^T, 2 K-steps x 4 N-tiles ----
    f32x4 ac0 = {0.f, 0.f, 0.f, 0.f}, ac1 = ac0, ac2 = ac0, ac3 = ac0;
#pragma unroll
    for (int ks = 0; ks < 2; ++ks) {
        bf16x8 af = *(const bf16x8*)(xw + q * 72 + g * 8 + ks * 32);
        bf16x8 b0 = *(const bf16x8*)(wt + (q +  0) * 72 + g * 8 + ks * 32);
        bf16x8 b1 = *(const bf16x8*)(wt + (q + 16) * 72 + g * 8 + ks * 32);
        bf16x8 b2 = *(const bf16x8*)(wt + (q + 32) * 72 + g * 8 + ks * 32);
        bf16x8 b3 = *(const bf16x8*)(wt + (q + 48) * 72 + g * 8 + ks * 32);
        ac0 = __builtin_amdgcn_mfma_f32_16x16x32_bf16(af, b0, ac0, 0, 0, 0);
        ac1 = __builtin_amdgcn_mfma_f32_16x16x32_bf16(af, b1, ac1, 0, 0, 0);
        ac2 = __builtin_amdgcn_mfma_f32_16x16x32_bf16(af, b2, ac2, 0, 0, 0);
        ac3 = __builtin_amdgcn_mfma_f32_16x16x32_bf16(af, b3, ac3, 0, 0, 0);
    }

    // ---- bias + leaky_relu + L2 norm + store ----
    // lane holds D[row=g*4+r][col=q+16t] for t,r in 0..3
    float dv[4][4];
    float ss[4] = {0.f, 0.f, 0.f, 0.f};
#pragma unroll
    for (int t = 0; t < 4; ++t) {
        f32x4 a = (t == 0) ? ac0 : (t == 1) ? ac1 : (t == 2) ? ac2 : ac3;
#pragma unroll
        for (int r = 0; r < 4; ++r) {
            float d = a[r] + bias[t];
            d = (d > 0.f) ? d : 0.01f * d;
            dv[t][r] = d;
            ss[r] = fmaf(d, d, ss[r]);
        }
    }
#pragma unroll
    for (int r = 0; r < 4; ++r) {
        float s2 = ss[r];
        s2 += __shfl_xor(s2, 1);
        s2 += __shfl_xor(s2, 2);
        s2 += __shfl_xor(s2, 4);
        s2 += __shfl_xor(s2, 8);
        float scl = 1.0f / fmaxf(sqrtf(s2), 1e-12f);
        int orow = rowW + g * 4 + r;
        if (orow < n) {
#pragma unroll
            for (int t = 0; t < 4; ++t) {
                float outv = dv[t][r] * scl;
                size_t cidx = (size_t)orow * EMB + 16 * t + q;
                if (yb) yb[cidx] = bf16_rne(outv);
                else    yf[cidx] = outv;
            }
        }
    }
}

// ---------------- launch ----------------

extern "C" void kernel_launch(void* const* d_in, const int* in_sizes, int n_in,
                              void* d_out, int out_size, void* d_ws, size_t ws_size,
                              hipStream_t stream) {
    const float* user_emb = (const float*)d_in[0];
    const float* item_emb = (const float*)d_in[1];
    const float* Wu0 = (const float*)d_in[2];
    const float* bu0 = (const float*)d_in[3];
    const float* Wu1 = (const float*)d_in[4];
    const float* bu1 = (const float*)d_in[5];
    const float* Wi0 = (const float*)d_in[6];
    const float* bi0 = (const float*)d_in[7];
    const float* Wi1 = (const float*)d_in[8];
    const float* bi1 = (const float*)d_in[9];
    const int*   u_rows = (const int*)d_in[10];
    const int*   u_cols = (const int*)d_in[11];
    const float* u_vals = (const float*)d_in[12];
    const int*   i_rows = (const int*)d_in[13];
    const int*   i_cols = (const int*)d_in[14];
    const float* i_vals = (const float*)d_in[15];

    const int nu = in_sizes[0] / EMB;
    const int ni = in_sizes[1] / EMB;
    const int eu = in_sizes[10];
    const int ei = in_sizes[13];

    const int BU = 512, BI = 256;
    const int RPBU = (nu + BU - 1) / BU;   // 196
    const int RPBI = (ni + BI - 1) / BI;   // 196

    float* out_u = (float*)d_out;
    float* out_i = out_u + (size_t)nu * EMB;

    // workspace carve (256B aligned)
    size_t o = 0;
    char* wsb = (char*)d_ws;
    auto carve = [&](size_t bytes) -> void* {
        void* p = wsb + o;
        o += (bytes + 255) & ~(size_t)255;
        return p;
    };
    ushort* xbu0 = (ushort*)carve((size_t)nu * EMB * 2);   // bf16 cast of user_emb
    ushort* xbi0 = (ushort*)carve((size_t)ni * EMB * 2);   // bf16 cast of item_emb
    int2* binnedU = (int2*)carve((size_t)BU * CAPB * 8);   // becomes CSR records in place
    int2* binnedI = (int2*)carve((size_t)BI * CAPB * 8);
    ushort* xbu1 = (ushort*)carve((size_t)nu * EMB * 2);   // layer-0 outputs (bf16)
    ushort* xbi1 = (ushort*)carve((size_t)ni * EMB * 2);
    int2* offseU = (int2*)carve((size_t)nu * 8);           // per-row (start,end)
    int2* offseI = (int2*)carve((size_t)ni * 8);
    ushort* wpkU0 = (ushort*)carve(4096 * 2);              // packed bf16 weights
    ushort* wpkI0 = (ushort*)carve(4096 * 2);
    ushort* wpkU1 = (ushort*)carve(4096 * 2);
    ushort* wpkI1 = (ushort*)carve(4096 * 2);
    int*  gcur  = (int*)carve((size_t)(BU + BI) * 16 * 4); // one memset covers both
    int*  gcurU = gcur;
    int*  gcurI = gcur + (size_t)BU * 16;
    (void)ws_size;

    // ---- CSR build via bucket sort + embedding cast + W pack, compacted launches ----
    hipMemsetAsync(gcur, 0, (size_t)(BU + BI) * 16 * 4, stream);
    {
        int nbU = (eu + CHUNK - 1) / CHUNK;
        int nbI = (ei + CHUNK - 1) / CHUNK;
        long n4u = (long)nu * EMB / 4, n4i = (long)ni * EMB / 4;
        int nbCast = (int)((n4u + n4i + 1023) / 1024);
        prep<<<nbU + nbI + nbCast + 4, 256, 0, stream>>>(
            u_rows, u_cols, u_vals, eu, BU, RPBU, gcurU, binnedU, nbU,
            i_rows, i_cols, i_vals, ei, BI, RPBI, gcurI, binnedI, nbI,
            (const float4*)user_emb, xbu0, n4u,
            (const float4*)item_emb, xbi0, n4i, nbCast,
            (const float4*)Wu0, wpkU0, (const float4*)Wi0, wpkI0,
            (const float4*)Wu1, wpkU1, (const float4*)Wi1, wpkI1);
    }
    finalize_csr<<<BU + BI, 256, 0, stream>>>(
        binnedU, gcurU, RPBU, nu, offseU, BU,
        binnedI, gcurI, RPBI, ni, offseI);

    // ---- 2 GCN layers, fused per layer; ping-pong bf16 buffers ----
    int ntU = (nu + 63) >> 6, ntI = (ni + 63) >> 6;
    // layer 0: bf16(emb) -> bf16 tmp
    spmm_mfma<<<ntU + ntI, 256, 0, stream>>>(
        offseU, binnedU, xbu0, wpkU0, bu0, nullptr, xbu1, nu, ntU,
        offseI, binnedI, xbi0, wpkI0, bi0, nullptr, xbi1, ni);
    // layer 1: bf16 tmp -> f32 out
    spmm_mfma<<<ntU + ntI, 256, 0, stream>>>(
        offseU, binnedU, xbu1, wpkU1, bu1, out_u, nullptr, nu, ntU,
        offseI, binnedI, xbi1, wpkI1, bi1, out_i, nullptr, ni);
}